// Round 1
// baseline (394.525 us; speedup 1.0000x reference)
//
#include <hip/hip_runtime.h>

typedef _Float16 f16;
typedef _Float16 f16x8 __attribute__((ext_vector_type(8)));
typedef _Float16 f16x4 __attribute__((ext_vector_type(4)));
typedef float f32x4 __attribute__((ext_vector_type(4)));

// Problem constants
#define SEQ 2048
#define DIM 128
#define QT 64          // q rows per block (4 waves x 16)
#define KTILE 64       // keys per tile
#define VT_STRIDE 76   // elems per transposed-V row (152B: 8B-aligned, 4-way write conflicts)
#define P_STRIDE 72    // elems per P row (144B: 16B-aligned)

__global__ __launch_bounds__(256, 2)
void attn_fwd(const float* __restrict__ Qg, const float* __restrict__ Kg,
              const float* __restrict__ Vg, const int* __restrict__ Mg,
              float* __restrict__ Og) {
  __shared__ __align__(16) unsigned short K_lds[QT * DIM];          // swizzled row-major f16
  __shared__ __align__(16) unsigned short Vt_lds[DIM * VT_STRIDE];  // transposed f16
  __shared__ __align__(16) unsigned short P_lds[QT * P_STRIDE];     // per-wave-private rows
  __shared__ int M_lds[KTILE];

  const int tid  = threadIdx.x;
  const int lane = tid & 63;
  const int w    = tid >> 6;     // wave 0..3
  const int li   = lane & 15;    // lane-in-group
  const int g    = lane >> 4;    // 16-lane group 0..3

  // XCD-aware swizzle (2048 % 8 == 0 -> bijective): each XCD gets 8 whole heads
  const int bid  = blockIdx.x;
  const int nid  = (bid & 7) * 256 + (bid >> 3);
  const int head = nid >> 5;     // 0..63  (= b*16 + h)
  const int qblk = nid & 31;     // 0..31
  const size_t hbase = (size_t)head * SEQ * DIM;
  const int bb = head >> 4;      // batch index for mask

  // ---- Q fragments (A-operand, f16), held in registers for the whole block ----
  f16x8 qf[4];
  {
    const float* qp = Qg + hbase + (size_t)(qblk * QT + w * 16 + li) * DIM + g * 8;
#pragma unroll
    for (int d0 = 0; d0 < 4; ++d0) {
      float4 a = *(const float4*)(qp + d0 * 32);
      float4 b = *(const float4*)(qp + d0 * 32 + 4);
      f16x8 f;
      f[0]=(f16)a.x; f[1]=(f16)a.y; f[2]=(f16)a.z; f[3]=(f16)a.w;
      f[4]=(f16)b.x; f[5]=(f16)b.y; f[6]=(f16)b.z; f[7]=(f16)b.w;
      qf[d0] = f;
    }
  }

  float mrow[4], lrow[4];
  f32x4 oacc[8];
#pragma unroll
  for (int r = 0; r < 4; ++r) { mrow[r] = -INFINITY; lrow[r] = 0.f; }
#pragma unroll
  for (int dt = 0; dt < 8; ++dt) oacc[dt] = (f32x4)(0.f);

  for (int t = 0; t < SEQ / KTILE; ++t) {
    const int k0 = t * KTILE;
    __syncthreads();   // previous tile's LDS reads done before overwrite

    // ---- stage K tile: f32 -> f16, XOR-swizzled rows ----
    {
      const float4* kgp = (const float4*)(Kg + hbase + (size_t)k0 * DIM);
#pragma unroll
      for (int rr = 0; rr < 8; ++rr) {
        int fi   = rr * 256 + tid;       // float4 index in 64x32
        int krow = fi >> 5;
        int d4   = fi & 31;
        float4 v = kgp[fi];
        union { f16 h[4]; uint2 u; } c;
        c.h[0]=(f16)v.x; c.h[1]=(f16)v.y; c.h[2]=(f16)v.z; c.h[3]=(f16)v.w;
        int off = krow * 256 + ((d4 * 8) ^ ((krow & 7) << 4));
        *(uint2*)((char*)K_lds + off) = c.u;
      }
    }
    // ---- stage V tile transposed: Vt[d][k], pack 2 f16 along k per u32 write ----
    {
      const float* vgp = Vg + hbase + (size_t)k0 * DIM;
#pragma unroll
      for (int rr = 0; rr < 16; ++rr) {
        int u  = rr * 256 + tid;
        int d  = u & 127;
        int k2 = (u >> 7) * 2;
        float v0 = vgp[(size_t)k2 * DIM + d];
        float v1 = vgp[(size_t)(k2 + 1) * DIM + d];
        union { f16 h[2]; unsigned int u32; } c;
        c.h[0]=(f16)v0; c.h[1]=(f16)v1;
        *(unsigned int*)(Vt_lds + d * VT_STRIDE + k2) = c.u32;
      }
    }
    if (tid < KTILE) M_lds[tid] = Mg[(size_t)bb * SEQ + k0 + tid];
    __syncthreads();

    // ---- QK^T: S[16q x 64k] per wave, fp32 accumulate over D ----
    f32x4 sacc[4];
#pragma unroll
    for (int kt = 0; kt < 4; ++kt) sacc[kt] = (f32x4)(0.f);
#pragma unroll
    for (int kt = 0; kt < 4; ++kt) {
      const int krow = kt * 16 + li;
      const int swz  = (krow & 7) << 4;
#pragma unroll
      for (int d0 = 0; d0 < 4; ++d0) {
        f16x8 kf = *(const f16x8*)((const char*)K_lds + krow * 256 + ((d0 * 64 + g * 16) ^ swz));
        sacc[kt] = __builtin_amdgcn_mfma_f32_16x16x32_f16(qf[d0], kf, sacc[kt], 0, 0, 0);
      }
    }

    // ---- mask (replace, matching jnp.where) + online softmax ----
    float tmax[4] = {-INFINITY, -INFINITY, -INFINITY, -INFINITY};
#pragma unroll
    for (int kt = 0; kt < 4; ++kt) {
      const bool ok = (M_lds[kt * 16 + li] != 0);
#pragma unroll
      for (int r = 0; r < 4; ++r) {
        float s = ok ? sacc[kt][r] : -1e9f;
        sacc[kt][r] = s;
        tmax[r] = fmaxf(tmax[r], s);
      }
    }
#pragma unroll
    for (int r = 0; r < 4; ++r) {
      tmax[r] = fmaxf(tmax[r], __shfl_xor(tmax[r], 1));
      tmax[r] = fmaxf(tmax[r], __shfl_xor(tmax[r], 2));
      tmax[r] = fmaxf(tmax[r], __shfl_xor(tmax[r], 4));
      tmax[r] = fmaxf(tmax[r], __shfl_xor(tmax[r], 8));
    }
    float sc[4], psum[4];
#pragma unroll
    for (int r = 0; r < 4; ++r) {
      float mnew = fmaxf(mrow[r], tmax[r]);
      sc[r]   = __expf(mrow[r] - mnew);   // -inf first tile -> 0
      mrow[r] = mnew;
      psum[r] = 0.f;
    }
#pragma unroll
    for (int dt = 0; dt < 8; ++dt)
#pragma unroll
      for (int r = 0; r < 4; ++r) oacc[dt][r] *= sc[r];
#pragma unroll
    for (int kt = 0; kt < 4; ++kt) {
#pragma unroll
      for (int r = 0; r < 4; ++r) {
        float p = __expf(sacc[kt][r] - mrow[r]);
        psum[r] += p;
        P_lds[(w * 16 + g * 4 + r) * P_STRIDE + kt * 16 + li] =
            __builtin_bit_cast(unsigned short, (f16)p);
      }
    }
#pragma unroll
    for (int r = 0; r < 4; ++r) {
      psum[r] += __shfl_xor(psum[r], 1);
      psum[r] += __shfl_xor(psum[r], 2);
      psum[r] += __shfl_xor(psum[r], 4);
      psum[r] += __shfl_xor(psum[r], 8);
      lrow[r] = lrow[r] * sc[r] + psum[r];
    }

    // ---- PV: oacc[16q x 128d] += P[16q x 64k] * V[64k x 128d] ----
#pragma unroll
    for (int c = 0; c < 2; ++c) {
      f16x8 pa = *(const f16x8*)(P_lds + (w * 16 + li) * P_STRIDE + c * 32 + g * 8);
#pragma unroll
      for (int dt = 0; dt < 8; ++dt) {
        const unsigned short* vp = Vt_lds + (dt * 16 + li) * VT_STRIDE + c * 32 + g * 8;
        f16x4 v0 = *(const f16x4*)vp;
        f16x4 v1 = *(const f16x4*)(vp + 4);
        f16x8 vf;
        vf[0]=v0[0]; vf[1]=v0[1]; vf[2]=v0[2]; vf[3]=v0[3];
        vf[4]=v1[0]; vf[5]=v1[1]; vf[6]=v1[2]; vf[7]=v1[3];
        oacc[dt] = __builtin_amdgcn_mfma_f32_16x16x32_f16(pa, vf, oacc[dt], 0, 0, 0);
      }
    }
  }

  // ---- epilogue: normalize and store ----
#pragma unroll
  for (int r = 0; r < 4; ++r) {
    float inv = 1.0f / lrow[r];
    float* op = Og + hbase + (size_t)(qblk * QT + w * 16 + g * 4 + r) * DIM + li;
#pragma unroll
    for (int dt = 0; dt < 8; ++dt) op[dt * 16] = oacc[dt][r] * inv;
  }
}

extern "C" void kernel_launch(void* const* d_in, const int* in_sizes, int n_in,
                              void* d_out, int out_size, void* d_ws, size_t ws_size,
                              hipStream_t stream) {
  (void)in_sizes; (void)n_in; (void)out_size; (void)d_ws; (void)ws_size;
  const float* Q = (const float*)d_in[0];
  const float* K = (const float*)d_in[1];
  const float* V = (const float*)d_in[2];
  const int*   M = (const int*)d_in[3];
  float*       O = (float*)d_out;
  attn_fwd<<<dim3(2048), dim3(256), 0, stream>>>(Q, K, V, M, O);
}

// Round 3
// 346.499 us; speedup vs baseline: 1.1386x; 1.1386x over previous
//
#include <hip/hip_runtime.h>

typedef _Float16 f16;
typedef _Float16 f16x8 __attribute__((ext_vector_type(8)));
typedef _Float16 f16x4 __attribute__((ext_vector_type(4)));
typedef float f32x4 __attribute__((ext_vector_type(4)));
typedef unsigned short ushort_t;

#define SEQ 2048
#define DIM 128
#define QT 64
#define KTILE 64
#define NT (SEQ / KTILE)      // 32 tiles
#define TILE_BYTES 16384      // 64x128 f16 (or 128x64 for Vt) = 16 KB
#define P_STRIDE 72

typedef __attribute__((address_space(3))) char lds_char;
typedef __attribute__((address_space(1))) const char glb_char;

__device__ __forceinline__ void gload16(const void* g, void* l) {
  __builtin_amdgcn_global_load_lds((glb_char*)g, (lds_char*)l, 16, 0, 0);
}

// ---------------- pre-pass: K -> f16, swizzled 64x128 tile images ----------------
// f16 (krow,d) of tile -> byte  krow*256 + (((d>>3) ^ (krow&7))<<4) + (d&7)*2
__global__ __launch_bounds__(256)
void prep_k(const float* __restrict__ Kg, char* __restrict__ Kws) {
  const int tid = threadIdx.x;
  const int blk = blockIdx.x;                 // (head*32 + tile), rows are contiguous
  const float* in = Kg + (size_t)blk * (KTILE * DIM);
  char* out = Kws + (size_t)blk * TILE_BYTES;
#pragma unroll
  for (int i = 0; i < 4; ++i) {
    int u = i * 256 + tid;                    // unit id 0..1023
    int krow = u >> 4;
    int un   = u & 15;                        // 8-f16 unit within row
    const float* p = in + krow * DIM + un * 8;
    float4 a = *(const float4*)p;
    float4 b = *(const float4*)(p + 4);
    union { f16 h[8]; uint4 u4; } c;
    c.h[0]=(f16)a.x; c.h[1]=(f16)a.y; c.h[2]=(f16)a.z; c.h[3]=(f16)a.w;
    c.h[4]=(f16)b.x; c.h[5]=(f16)b.y; c.h[6]=(f16)b.z; c.h[7]=(f16)b.w;
    *(uint4*)(out + krow * 256 + ((un ^ (krow & 7)) << 4)) = c.u4;
  }
}

// ---------------- pre-pass: V -> f16 transposed, swizzled 128x64 tile images ----------------
// f16 (k,d) of tile -> byte  d*128 + (((k>>3) ^ (d&7))<<4) + (k&7)*2
__global__ __launch_bounds__(256)
void prep_v(const float* __restrict__ Vg, char* __restrict__ Vws) {
  __shared__ ushort_t Vs[KTILE * 133];        // row-major [k][d], pad 133 (conflict-free col reads)
  const int tid = threadIdx.x;
  const int blk = blockIdx.x;
  const float* in = Vg + (size_t)blk * (KTILE * DIM);
  char* out = Vws + (size_t)blk * TILE_BYTES;
#pragma unroll
  for (int i = 0; i < 4; ++i) {
    int u = i * 256 + tid;
    int k  = u >> 4;
    int d0 = (u & 15) * 8;
    const float* p = in + k * DIM + d0;
    float4 a = *(const float4*)p;
    float4 b = *(const float4*)(p + 4);
    f16 h[8];
    h[0]=(f16)a.x; h[1]=(f16)a.y; h[2]=(f16)a.z; h[3]=(f16)a.w;
    h[4]=(f16)b.x; h[5]=(f16)b.y; h[6]=(f16)b.z; h[7]=(f16)b.w;
#pragma unroll
    for (int j = 0; j < 8; ++j)
      Vs[k * 133 + d0 + j] = __builtin_bit_cast(ushort_t, h[j]);
  }
  __syncthreads();
#pragma unroll
  for (int i = 0; i < 4; ++i) {
    int u = i * 256 + tid;
    int d  = u >> 3;
    int un = u & 7;                           // 8-k unit within Vt row
    union { f16 h[8]; uint4 u4; } c;
#pragma unroll
    for (int j = 0; j < 8; ++j)
      c.h[j] = __builtin_bit_cast(f16, Vs[(un * 8 + j) * 133 + d]);
    *(uint4*)(out + d * 128 + ((un ^ (d & 7)) << 4)) = c.u4;
  }
}

// ---------------- main: flash attention, f16 MFMA, double-buffered gload_lds ----------------
__global__ __launch_bounds__(256, 2)
void attn_main(const float* __restrict__ Qg, const char* __restrict__ Kws,
               const char* __restrict__ Vws, const int* __restrict__ Mg,
               float* __restrict__ Og) {
  __shared__ __align__(16) char Kb[2][TILE_BYTES];
  __shared__ __align__(16) char Vb[2][TILE_BYTES];
  __shared__ __align__(16) ushort_t P_lds[QT * P_STRIDE];
  __shared__ int Mb[2][KTILE];

  const int tid  = threadIdx.x;
  const int lane = tid & 63;
  const int w    = tid >> 6;
  const int li   = lane & 15;
  const int g    = lane >> 4;

  const int bid  = blockIdx.x;
  const int nid  = (bid & 7) * 256 + (bid >> 3);   // XCD swizzle (2048%8==0, bijective)
  const int head = nid >> 5;
  const int qblk = nid & 31;
  const size_t hbase = (size_t)head * SEQ * DIM;
  const int bb = head >> 4;

  const char* ktb = Kws + ((size_t)(head * NT) << 14);
  const char* vtb = Vws + ((size_t)(head * NT) << 14);

  // Q fragments (A-operand), f32->f16 once
  f16x8 qf[4];
  {
    const float* qp = Qg + hbase + (size_t)(qblk * QT + w * 16 + li) * DIM + g * 8;
#pragma unroll
    for (int d0 = 0; d0 < 4; ++d0) {
      float4 a = *(const float4*)(qp + d0 * 32);
      float4 b = *(const float4*)(qp + d0 * 32 + 4);
      f16x8 f;
      f[0]=(f16)a.x; f[1]=(f16)a.y; f[2]=(f16)a.z; f[3]=(f16)a.w;
      f[4]=(f16)b.x; f[5]=(f16)b.y; f[6]=(f16)b.z; f[7]=(f16)b.w;
      qf[d0] = f;
    }
  }

  float mrow[4], lrow[4];
  f32x4 oacc[8];
#pragma unroll
  for (int r = 0; r < 4; ++r) { mrow[r] = -INFINITY; lrow[r] = 0.f; }
#pragma unroll
  for (int dt = 0; dt < 8; ++dt) oacc[dt] = (f32x4)(0.f);

  // prologue: stage tile 0 into buffer 0
  {
#pragma unroll
    for (int i = 0; i < 4; ++i) {
      int seg = i * 4 + w;                      // 16 x 1KB segments
      gload16(ktb + seg * 1024 + lane * 16, &Kb[0][seg * 1024]);
      gload16(vtb + seg * 1024 + lane * 16, &Vb[0][seg * 1024]);
    }
    if (tid < KTILE) Mb[0][tid] = Mg[(size_t)bb * SEQ + tid];
  }
  __syncthreads();

  int cur = 0;
  for (int t = 0; t < NT; ++t) {
    // ---- issue next tile's staging (overlaps with compute below) ----
    int mreg = 0;
    if (t + 1 < NT) {
      const char* kt2 = ktb + ((size_t)(t + 1) << 14);
      const char* vt2 = vtb + ((size_t)(t + 1) << 14);
      const int nb = cur ^ 1;
#pragma unroll
      for (int i = 0; i < 4; ++i) {
        int seg = i * 4 + w;
        gload16(kt2 + seg * 1024 + lane * 16, &Kb[nb][seg * 1024]);
        gload16(vt2 + seg * 1024 + lane * 16, &Vb[nb][seg * 1024]);
      }
      if (tid < KTILE) mreg = Mg[(size_t)bb * SEQ + (t + 1) * KTILE + tid];
    }

    // ---- QK^T ----
    f32x4 sacc[4];
#pragma unroll
    for (int kt = 0; kt < 4; ++kt) sacc[kt] = (f32x4)(0.f);
#pragma unroll
    for (int kt = 0; kt < 4; ++kt) {
      const int krow = kt * 16 + li;
#pragma unroll
      for (int d0 = 0; d0 < 4; ++d0) {
        f16x8 kf = *(const f16x8*)(&Kb[cur][krow * 256 + (((d0 * 4 + g) ^ (krow & 7)) << 4)]);
        sacc[kt] = __builtin_amdgcn_mfma_f32_16x16x32_f16(qf[d0], kf, sacc[kt], 0, 0, 0);
      }
    }

    // ---- mask + online softmax ----
    float tmax[4] = {-INFINITY, -INFINITY, -INFINITY, -INFINITY};
#pragma unroll
    for (int kt = 0; kt < 4; ++kt) {
      const bool ok = (Mb[cur][kt * 16 + li] != 0);
#pragma unroll
      for (int r = 0; r < 4; ++r) {
        float s = ok ? sacc[kt][r] : -1e9f;
        sacc[kt][r] = s;
        tmax[r] = fmaxf(tmax[r], s);
      }
    }
#pragma unroll
    for (int r = 0; r < 4; ++r) {
      tmax[r] = fmaxf(tmax[r], __shfl_xor(tmax[r], 1));
      tmax[r] = fmaxf(tmax[r], __shfl_xor(tmax[r], 2));
      tmax[r] = fmaxf(tmax[r], __shfl_xor(tmax[r], 4));
      tmax[r] = fmaxf(tmax[r], __shfl_xor(tmax[r], 8));
    }
    float sc[4], psum[4];
#pragma unroll
    for (int r = 0; r < 4; ++r) {
      float mnew = fmaxf(mrow[r], tmax[r]);
      sc[r]   = __expf(mrow[r] - mnew);
      mrow[r] = mnew;
      psum[r] = 0.f;
    }
#pragma unroll
    for (int dt = 0; dt < 8; ++dt)
#pragma unroll
      for (int r = 0; r < 4; ++r) oacc[dt][r] *= sc[r];
#pragma unroll
    for (int kt = 0; kt < 4; ++kt) {
#pragma unroll
      for (int r = 0; r < 4; ++r) {
        float p = __expf(sacc[kt][r] - mrow[r]);
        psum[r] += p;
        P_lds[(w * 16 + g * 4 + r) * P_STRIDE + kt * 16 + li] =
            __builtin_bit_cast(ushort_t, (f16)p);
      }
    }
#pragma unroll
    for (int r = 0; r < 4; ++r) {
      psum[r] += __shfl_xor(psum[r], 1);
      psum[r] += __shfl_xor(psum[r], 2);
      psum[r] += __shfl_xor(psum[r], 4);
      psum[r] += __shfl_xor(psum[r], 8);
      lrow[r] = lrow[r] * sc[r] + psum[r];
    }

    // ---- PV ----
#pragma unroll
    for (int c = 0; c < 2; ++c) {
      f16x8 pa = *(const f16x8*)(P_lds + (w * 16 + li) * P_STRIDE + c * 32 + g * 8);
#pragma unroll
      for (int dt = 0; dt < 8; ++dt) {
        const int d = dt * 16 + li;
        f16x8 vf = *(const f16x8*)(&Vb[cur][d * 128 + (((c * 4 + g) ^ (d & 7)) << 4)]);
        oacc[dt] = __builtin_amdgcn_mfma_f32_16x16x32_f16(pa, vf, oacc[dt], 0, 0, 0);
      }
    }

    // publish next mask, drain staging, flip
    if (t + 1 < NT && tid < KTILE) Mb[cur ^ 1][tid] = mreg;
    __syncthreads();
    cur ^= 1;
  }

  // ---- epilogue ----
#pragma unroll
  for (int r = 0; r < 4; ++r) {
    float inv = 1.0f / lrow[r];
    float* op = Og + hbase + (size_t)(qblk * QT + w * 16 + g * 4 + r) * DIM + li;
#pragma unroll
    for (int dt = 0; dt < 8; ++dt) op[dt * 16] = oacc[dt][r] * inv;
  }
}

// ---------------- fallback (verified round-1 kernel) for small ws ----------------
#define VT_STRIDE 76
__global__ __launch_bounds__(256, 2)
void attn_fwd_fb(const float* __restrict__ Qg, const float* __restrict__ Kg,
                 const float* __restrict__ Vg, const int* __restrict__ Mg,
                 float* __restrict__ Og) {
  __shared__ __align__(16) ushort_t K_lds[QT * DIM];
  __shared__ __align__(16) ushort_t Vt_lds[DIM * VT_STRIDE];
  __shared__ __align__(16) ushort_t P_lds[QT * P_STRIDE];
  __shared__ int M_lds[KTILE];
  const int tid  = threadIdx.x;
  const int lane = tid & 63;
  const int w    = tid >> 6;
  const int li   = lane & 15;
  const int g    = lane >> 4;
  const int bid  = blockIdx.x;
  const int nid  = (bid & 7) * 256 + (bid >> 3);
  const int head = nid >> 5;
  const int qblk = nid & 31;
  const size_t hbase = (size_t)head * SEQ * DIM;
  const int bb = head >> 4;
  f16x8 qf[4];
  {
    const float* qp = Qg + hbase + (size_t)(qblk * QT + w * 16 + li) * DIM + g * 8;
#pragma unroll
    for (int d0 = 0; d0 < 4; ++d0) {
      float4 a = *(const float4*)(qp + d0 * 32);
      float4 b = *(const float4*)(qp + d0 * 32 + 4);
      f16x8 f;
      f[0]=(f16)a.x; f[1]=(f16)a.y; f[2]=(f16)a.z; f[3]=(f16)a.w;
      f[4]=(f16)b.x; f[5]=(f16)b.y; f[6]=(f16)b.z; f[7]=(f16)b.w;
      qf[d0] = f;
    }
  }
  float mrow[4], lrow[4];
  f32x4 oacc[8];
#pragma unroll
  for (int r = 0; r < 4; ++r) { mrow[r] = -INFINITY; lrow[r] = 0.f; }
#pragma unroll
  for (int dt = 0; dt < 8; ++dt) oacc[dt] = (f32x4)(0.f);
  for (int t = 0; t < NT; ++t) {
    const int k0 = t * KTILE;
    __syncthreads();
    {
      const float4* kgp = (const float4*)(Kg + hbase + (size_t)k0 * DIM);
#pragma unroll
      for (int rr = 0; rr < 8; ++rr) {
        int fi = rr * 256 + tid;
        int krow = fi >> 5;
        int d4 = fi & 31;
        float4 v = kgp[fi];
        union { f16 h[4]; uint2 u; } c;
        c.h[0]=(f16)v.x; c.h[1]=(f16)v.y; c.h[2]=(f16)v.z; c.h[3]=(f16)v.w;
        int off = krow * 256 + ((d4 * 8) ^ ((krow & 7) << 4));
        *(uint2*)((char*)K_lds + off) = c.u;
      }
    }
    {
      const float* vgp = Vg + hbase + (size_t)k0 * DIM;
#pragma unroll
      for (int rr = 0; rr < 16; ++rr) {
        int u = rr * 256 + tid;
        int d = u & 127;
        int k2 = (u >> 7) * 2;
        float v0 = vgp[(size_t)k2 * DIM + d];
        float v1 = vgp[(size_t)(k2 + 1) * DIM + d];
        union { f16 h[2]; unsigned int u32; } c;
        c.h[0]=(f16)v0; c.h[1]=(f16)v1;
        *(unsigned int*)(Vt_lds + d * VT_STRIDE + k2) = c.u32;
      }
    }
    if (tid < KTILE) M_lds[tid] = Mg[(size_t)bb * SEQ + k0 + tid];
    __syncthreads();
    f32x4 sacc[4];
#pragma unroll
    for (int kt = 0; kt < 4; ++kt) sacc[kt] = (f32x4)(0.f);
#pragma unroll
    for (int kt = 0; kt < 4; ++kt) {
      const int krow = kt * 16 + li;
      const int swz = (krow & 7) << 4;
#pragma unroll
      for (int d0 = 0; d0 < 4; ++d0) {
        f16x8 kf = *(const f16x8*)((const char*)K_lds + krow * 256 + ((d0 * 64 + g * 16) ^ swz));
        sacc[kt] = __builtin_amdgcn_mfma_f32_16x16x32_f16(qf[d0], kf, sacc[kt], 0, 0, 0);
      }
    }
    float tmax[4] = {-INFINITY, -INFINITY, -INFINITY, -INFINITY};
#pragma unroll
    for (int kt = 0; kt < 4; ++kt) {
      const bool ok = (M_lds[kt * 16 + li] != 0);
#pragma unroll
      for (int r = 0; r < 4; ++r) {
        float s = ok ? sacc[kt][r] : -1e9f;
        sacc[kt][r] = s;
        tmax[r] = fmaxf(tmax[r], s);
      }
    }
#pragma unroll
    for (int r = 0; r < 4; ++r) {
      tmax[r] = fmaxf(tmax[r], __shfl_xor(tmax[r], 1));
      tmax[r] = fmaxf(tmax[r], __shfl_xor(tmax[r], 2));
      tmax[r] = fmaxf(tmax[r], __shfl_xor(tmax[r], 4));
      tmax[r] = fmaxf(tmax[r], __shfl_xor(tmax[r], 8));
    }
    float sc[4], psum[4];
#pragma unroll
    for (int r = 0; r < 4; ++r) {
      float mnew = fmaxf(mrow[r], tmax[r]);
      sc[r] = __expf(mrow[r] - mnew);
      mrow[r] = mnew;
      psum[r] = 0.f;
    }
#pragma unroll
    for (int dt = 0; dt < 8; ++dt)
#pragma unroll
      for (int r = 0; r < 4; ++r) oacc[dt][r] *= sc[r];
#pragma unroll
    for (int kt = 0; kt < 4; ++kt) {
#pragma unroll
      for (int r = 0; r < 4; ++r) {
        float p = __expf(sacc[kt][r] - mrow[r]);
        psum[r] += p;
        P_lds[(w * 16 + g * 4 + r) * P_STRIDE + kt * 16 + li] =
            __builtin_bit_cast(ushort_t, (f16)p);
      }
    }
#pragma unroll
    for (int r = 0; r < 4; ++r) {
      psum[r] += __shfl_xor(psum[r], 1);
      psum[r] += __shfl_xor(psum[r], 2);
      psum[r] += __shfl_xor(psum[r], 4);
      psum[r] += __shfl_xor(psum[r], 8);
      lrow[r] = lrow[r] * sc[r] + psum[r];
    }
#pragma unroll
    for (int c = 0; c < 2; ++c) {
      f16x8 pa = *(const f16x8*)(P_lds + (w * 16 + li) * P_STRIDE + c * 32 + g * 8);
#pragma unroll
      for (int dt = 0; dt < 8; ++dt) {
        const ushort_t* vp = Vt_lds + (dt * 16 + li) * VT_STRIDE + c * 32 + g * 8;
        f16x4 v0 = *(const f16x4*)vp;
        f16x4 v1 = *(const f16x4*)(vp + 4);
        f16x8 vf;
        vf[0]=v0[0]; vf[1]=v0[1]; vf[2]=v0[2]; vf[3]=v0[3];
        vf[4]=v1[0]; vf[5]=v1[1]; vf[6]=v1[2]; vf[7]=v1[3];
        oacc[dt] = __builtin_amdgcn_mfma_f32_16x16x32_f16(pa, vf, oacc[dt], 0, 0, 0);
      }
    }
  }
#pragma unroll
  for (int r = 0; r < 4; ++r) {
    float inv = 1.0f / lrow[r];
    float* op = Og + hbase + (size_t)(qblk * QT + w * 16 + g * 4 + r) * DIM + li;
#pragma unroll
    for (int dt = 0; dt < 8; ++dt) op[dt * 16] = oacc[dt][r] * inv;
  }
}

extern "C" void kernel_launch(void* const* d_in, const int* in_sizes, int n_in,
                              void* d_out, int out_size, void* d_ws, size_t ws_size,
                              hipStream_t stream) {
  (void)in_sizes; (void)n_in; (void)out_size;
  const float* Q = (const float*)d_in[0];
  const float* K = (const float*)d_in[1];
  const float* V = (const float*)d_in[2];
  const int*   M = (const int*)d_in[3];
  float*       O = (float*)d_out;

  const size_t half = (size_t)2048 * TILE_BYTES;   // 33.5 MB each
  if (ws_size >= 2 * half) {
    char* Kws = (char*)d_ws;
    char* Vws = Kws + half;
    prep_k<<<dim3(2048), dim3(256), 0, stream>>>(K, Kws);
    prep_v<<<dim3(2048), dim3(256), 0, stream>>>(V, Vws);
    attn_main<<<dim3(2048), dim3(256), 0, stream>>>(Q, Kws, Vws, M, O);
  } else {
    attn_fwd_fb<<<dim3(2048), dim3(256), 0, stream>>>(Q, K, V, M, O);
  }
}

// Round 4
// 210.428 us; speedup vs baseline: 1.8749x; 1.6466x over previous
//
#include <hip/hip_runtime.h>

typedef _Float16 f16;
typedef _Float16 f16x8 __attribute__((ext_vector_type(8)));
typedef _Float16 f16x4 __attribute__((ext_vector_type(4)));
typedef float f32x4 __attribute__((ext_vector_type(4)));
typedef float f32x16 __attribute__((ext_vector_type(16)));
typedef unsigned short ushort_t;
typedef unsigned int uint_t;

#define SEQ 2048
#define DIM 128
#define KVBLK 64
#define NT (SEQ / KVBLK)      // 32 k-tiles
#define TILE_BYTES 16384      // 64x128 (or 128x64) f16 tile image

typedef __attribute__((address_space(3))) char lds_char;
typedef __attribute__((address_space(1))) const char glb_char;

__device__ __forceinline__ void gload16(const void* g, void* l) {
  __builtin_amdgcn_global_load_lds((glb_char*)g, (lds_char*)l, 16, 0, 0);
}

// ---------------- pre-pass: K -> f16, swizzled 64x128 tile images ----------------
// f16 (krow,d) -> byte  krow*256 + (((d>>3) ^ (krow&7))<<4) + (d&7)*2   [verified R3]
__global__ __launch_bounds__(256)
void prep_k(const float* __restrict__ Kg, char* __restrict__ Kws) {
  const int tid = threadIdx.x;
  const int blk = blockIdx.x;                 // head*32 + tile
  const float* in = Kg + (size_t)blk * (KVBLK * DIM);
  char* out = Kws + (size_t)blk * TILE_BYTES;
#pragma unroll
  for (int i = 0; i < 4; ++i) {
    int u = i * 256 + tid;
    int krow = u >> 4;
    int un   = u & 15;
    const float* p = in + krow * DIM + un * 8;
    float4 a = *(const float4*)p;
    float4 b = *(const float4*)(p + 4);
    union { f16 h[8]; uint4 u4; } c;
    c.h[0]=(f16)a.x; c.h[1]=(f16)a.y; c.h[2]=(f16)a.z; c.h[3]=(f16)a.w;
    c.h[4]=(f16)b.x; c.h[5]=(f16)b.y; c.h[6]=(f16)b.z; c.h[7]=(f16)b.w;
    *(uint4*)(out + krow * 256 + ((un ^ (krow & 7)) << 4)) = c.u4;
  }
}

// ---------------- pre-pass: V -> f16 transposed, swizzled 128x64 tile images ----------------
// f16 (k,dv) -> byte  dv*128 + (((k>>3) ^ (dv&7))<<4) + (k&7)*2   [verified R3]
__global__ __launch_bounds__(256)
void prep_v(const float* __restrict__ Vg, char* __restrict__ Vws) {
  __shared__ ushort_t Vs[KVBLK * 133];
  const int tid = threadIdx.x;
  const int blk = blockIdx.x;
  const float* in = Vg + (size_t)blk * (KVBLK * DIM);
  char* out = Vws + (size_t)blk * TILE_BYTES;
#pragma unroll
  for (int i = 0; i < 4; ++i) {
    int u = i * 256 + tid;
    int k  = u >> 4;
    int d0 = (u & 15) * 8;
    const float* p = in + k * DIM + d0;
    float4 a = *(const float4*)p;
    float4 b = *(const float4*)(p + 4);
    f16 h[8];
    h[0]=(f16)a.x; h[1]=(f16)a.y; h[2]=(f16)a.z; h[3]=(f16)a.w;
    h[4]=(f16)b.x; h[5]=(f16)b.y; h[6]=(f16)b.z; h[7]=(f16)b.w;
#pragma unroll
    for (int j = 0; j < 8; ++j)
      Vs[k * 133 + d0 + j] = __builtin_bit_cast(ushort_t, h[j]);
  }
  __syncthreads();
#pragma unroll
  for (int i = 0; i < 4; ++i) {
    int u = i * 256 + tid;
    int d  = u >> 3;
    int un = u & 7;
    union { f16 h[8]; uint4 u4; } c;
#pragma unroll
    for (int j = 0; j < 8; ++j)
      c.h[j] = __builtin_bit_cast(f16, Vs[(un * 8 + j) * 133 + d]);
    *(uint4*)(out + d * 128 + ((un ^ (d & 7)) << 4)) = c.u4;
  }
}

// ---------------- main: 8 waves x QBLK32, 32x32x16 MFMA, swapped QK^T & PV ----------------
__global__ __launch_bounds__(512, 2)
void attn_main32(const float* __restrict__ Qg, const char* __restrict__ Kws,
                 const char* __restrict__ Vws, const int* __restrict__ Mg,
                 float* __restrict__ Og) {
  __shared__ __align__(16) char Kb[2][TILE_BYTES];
  __shared__ __align__(16) char Vb[2][TILE_BYTES];
  __shared__ float bias_s[2][KVBLK];

  const int tid  = threadIdx.x;
  const int lane = tid & 63;
  const int w    = tid >> 6;       // wave 0..7
  const int q32  = lane & 31;      // q within wave tile
  const int h    = lane >> 5;      // half 0/1

  // XCD grouping: same-XCD blocks share 4 heads' K/V (fits 4MB L2)
  const int bid  = blockIdx.x;                  // 0..511
  const int head = (bid & 7) * 8 + (bid >> 6);  // 0..63
  const int qblk = (bid >> 3) & 7;              // 0..7 (256 q-rows each)
  const size_t hbase = (size_t)head * SEQ * DIM;
  const int bb = head >> 4;

  const char* ktb = Kws + ((size_t)(head * NT) << 14);
  const char* vtb = Vws + ((size_t)(head * NT) << 14);

  const int qrow = qblk * 256 + w * 32 + q32;   // q within head

  // ---- Q fragments: lane holds Q[qrow][d = 16c + 8h + j], j=0..7 ----
  f16x8 qf[8];
  {
    const float* qp = Qg + hbase + (size_t)qrow * DIM + h * 8;
#pragma unroll
    for (int c = 0; c < 8; ++c) {
      float4 a = *(const float4*)(qp + c * 16);
      float4 b = *(const float4*)(qp + c * 16 + 4);
      f16x8 f;
      f[0]=(f16)a.x; f[1]=(f16)a.y; f[2]=(f16)a.z; f[3]=(f16)a.w;
      f[4]=(f16)b.x; f[5]=(f16)b.y; f[6]=(f16)b.z; f[7]=(f16)b.w;
      qf[c] = f;
    }
  }

  f32x16 oacc[4];
#pragma unroll
  for (int dvt = 0; dvt < 4; ++dvt) oacc[dvt] = (f32x16)(0.f);
  float mrow = -INFINITY, lrow = 0.f;

  // prologue: stage tile 0
  {
#pragma unroll
    for (int i = 0; i < 2; ++i) {
      int u = i * 512 + tid;
      gload16(ktb + u * 16, &Kb[0][u * 16]);
      gload16(vtb + u * 16, &Vb[0][u * 16]);
    }
    if (tid < KVBLK) bias_s[0][tid] = (Mg[(size_t)bb * SEQ + tid] != 0) ? 0.f : -1e9f;
  }
  __syncthreads();

  int cur = 0;
  for (int t = 0; t < NT; ++t) {
    // ---- issue next tile staging ----
    if (t + 1 < NT) {
      const char* kt2 = ktb + ((size_t)(t + 1) << 14);
      const char* vt2 = vtb + ((size_t)(t + 1) << 14);
      const int nb = cur ^ 1;
#pragma unroll
      for (int i = 0; i < 2; ++i) {
        int u = i * 512 + tid;
        gload16(kt2 + u * 16, &Kb[nb][u * 16]);
        gload16(vt2 + u * 16, &Vb[nb][u * 16]);
      }
      if (tid < KVBLK)
        bias_s[nb][tid] = (Mg[(size_t)bb * SEQ + (t + 1) * KVBLK + tid] != 0) ? 0.f : -1e9f;
    }

    // ---- QK^T (swapped): s[kt2] = K_tile^T-product, C-initialized with mask bias ----
    // lane holds S[q=q32][k = kt2*32 + crow(r,h)], crow(r,h) = (r&3)+8*(r>>2)+4h
    f32x16 s[2];
#pragma unroll
    for (int kt2 = 0; kt2 < 2; ++kt2) {
#pragma unroll
      for (int rq = 0; rq < 4; ++rq) {
        f32x4 b4 = *(const f32x4*)(&bias_s[cur][kt2 * 32 + rq * 8 + h * 4]);
        s[kt2][rq * 4 + 0] = b4[0]; s[kt2][rq * 4 + 1] = b4[1];
        s[kt2][rq * 4 + 2] = b4[2]; s[kt2][rq * 4 + 3] = b4[3];
      }
      const int krow = kt2 * 32 + q32;
      const int ksw  = krow & 7;
#pragma unroll
      for (int c = 0; c < 8; ++c) {
        f16x8 kf = *(const f16x8*)(&Kb[cur][krow * 256 + (((2 * c + h) ^ ksw) << 4)]);
        s[kt2] = __builtin_amdgcn_mfma_f32_32x32x16_f16(kf, qf[c], s[kt2], 0, 0, 0);
      }
    }

    // ---- online softmax (lane-local row) ----
    float pmax = s[0][0];
#pragma unroll
    for (int r = 1; r < 16; ++r) pmax = fmaxf(pmax, s[0][r]);
#pragma unroll
    for (int r = 0; r < 16; ++r) pmax = fmaxf(pmax, s[1][r]);
    pmax = fmaxf(pmax, __shfl_xor(pmax, 32));

    if (!__all(pmax - mrow <= 8.f)) {          // defer-max (T13)
      float mnew = fmaxf(mrow, pmax);
      float scf = __expf(mrow - mnew);
#pragma unroll
      for (int dvt = 0; dvt < 4; ++dvt)
#pragma unroll
        for (int r = 0; r < 16; ++r) oacc[dvt][r] *= scf;
      lrow *= scf;
      mrow = mnew;
    }

    float psum = 0.f;
#pragma unroll
    for (int t2 = 0; t2 < 2; ++t2)
#pragma unroll
      for (int r = 0; r < 16; ++r) {
        float p = __expf(s[t2][r] - mrow);
        s[t2][r] = p;
        psum += p;
      }
    psum += __shfl_xor(psum, 32);
    lrow += psum;

    // ---- pack P to f16 pairs: pkA[t2][m]=(p[4m],p[4m+1]), pkB=(p[4m+2],p[4m+3]) ----
    uint_t pkA[2][4], pkB[2][4];
#pragma unroll
    for (int t2 = 0; t2 < 2; ++t2)
#pragma unroll
      for (int m = 0; m < 4; ++m) {
        pkA[t2][m] = __builtin_bit_cast(uint_t,
            __builtin_amdgcn_cvt_pkrtz(s[t2][4 * m + 0], s[t2][4 * m + 1]));
        pkB[t2][m] = __builtin_bit_cast(uint_t,
            __builtin_amdgcn_cvt_pkrtz(s[t2][4 * m + 2], s[t2][4 * m + 3]));
      }

    // ---- PV (swapped): O^T += V^T * P^T ; pa[j] = P[q32][16ks+8h+j] ----
#pragma unroll
    for (int ks = 0; ks < 4; ++ks) {
      const int sk = ks & 1, tt = ks >> 1;
      uint_t Ao = h ? pkA[tt][2 * sk + 1] : pkA[tt][2 * sk];
      uint_t Bo = h ? pkB[tt][2 * sk + 1] : pkB[tt][2 * sk];
      uint_t As = h ? pkA[tt][2 * sk]     : pkA[tt][2 * sk + 1];
      uint_t Bs = h ? pkB[tt][2 * sk]     : pkB[tt][2 * sk + 1];
      uint_t Ax = (uint_t)__shfl_xor((int)As, 32);
      uint_t Bx = (uint_t)__shfl_xor((int)Bs, 32);
      union { uint_t u[4]; f16x8 v; } pa;
      pa.u[0] = h ? Ax : Ao;
      pa.u[1] = h ? Bx : Bo;
      pa.u[2] = h ? Ao : Ax;
      pa.u[3] = h ? Bo : Bx;
#pragma unroll
      for (int dvt = 0; dvt < 4; ++dvt) {
        const int dv = dvt * 32 + q32;
        f16x8 vf = *(const f16x8*)(&Vb[cur][dv * 128 + (((2 * ks + h) ^ (dv & 7)) << 4)]);
        oacc[dvt] = __builtin_amdgcn_mfma_f32_32x32x16_f16(vf, pa.v, oacc[dvt], 0, 0, 0);
      }
    }

    __syncthreads();
    cur ^= 1;
  }

  // ---- epilogue: O[q][dv] = oacc/lrow ; reg r of oacc[dvt] holds dv = 32dvt+crow(r,h) ----
  const float inv = 1.0f / lrow;
  float* op = Og + hbase + (size_t)qrow * DIM;
#pragma unroll
  for (int dvt = 0; dvt < 4; ++dvt)
#pragma unroll
    for (int rq = 0; rq < 4; ++rq) {
      float4 o4;
      o4.x = oacc[dvt][4 * rq + 0] * inv;
      o4.y = oacc[dvt][4 * rq + 1] * inv;
      o4.z = oacc[dvt][4 * rq + 2] * inv;
      o4.w = oacc[dvt][4 * rq + 3] * inv;
      *(float4*)(op + dvt * 32 + rq * 8 + h * 4) = o4;
    }
}

// ---------------- fallback (verified round-1 kernel) for small ws ----------------
#define QT 64
#define P_STRIDE 72
#define VT_STRIDE 76
typedef _Float16 f16x4_t __attribute__((ext_vector_type(4)));
__global__ __launch_bounds__(256, 2)
void attn_fwd_fb(const float* __restrict__ Qg, const float* __restrict__ Kg,
                 const float* __restrict__ Vg, const int* __restrict__ Mg,
                 float* __restrict__ Og) {
  __shared__ __align__(16) ushort_t K_lds[QT * DIM];
  __shared__ __align__(16) ushort_t Vt_lds[DIM * VT_STRIDE];
  __shared__ __align__(16) ushort_t P_lds[QT * P_STRIDE];
  __shared__ int M_lds[KVBLK];
  const int tid  = threadIdx.x;
  const int lane = tid & 63;
  const int w    = tid >> 6;
  const int li   = lane & 15;
  const int g    = lane >> 4;
  const int bid  = blockIdx.x;
  const int nid  = (bid & 7) * 256 + (bid >> 3);
  const int head = nid >> 5;
  const int qblk = nid & 31;
  const size_t hbase = (size_t)head * SEQ * DIM;
  const int bb = head >> 4;
  f16x8 qf[4];
  {
    const float* qp = Qg + hbase + (size_t)(qblk * QT + w * 16 + li) * DIM + g * 8;
#pragma unroll
    for (int d0 = 0; d0 < 4; ++d0) {
      float4 a = *(const float4*)(qp + d0 * 32);
      float4 b = *(const float4*)(qp + d0 * 32 + 4);
      f16x8 f;
      f[0]=(f16)a.x; f[1]=(f16)a.y; f[2]=(f16)a.z; f[3]=(f16)a.w;
      f[4]=(f16)b.x; f[5]=(f16)b.y; f[6]=(f16)b.z; f[7]=(f16)b.w;
      qf[d0] = f;
    }
  }
  float mrow[4], lrow[4];
  f32x4 oacc[8];
#pragma unroll
  for (int r = 0; r < 4; ++r) { mrow[r] = -INFINITY; lrow[r] = 0.f; }
#pragma unroll
  for (int dt = 0; dt < 8; ++dt) oacc[dt] = (f32x4)(0.f);
  for (int t = 0; t < NT; ++t) {
    const int k0 = t * KVBLK;
    __syncthreads();
    {
      const float4* kgp = (const float4*)(Kg + hbase + (size_t)k0 * DIM);
#pragma unroll
      for (int rr = 0; rr < 8; ++rr) {
        int fi = rr * 256 + tid;
        int krow = fi >> 5;
        int d4 = fi & 31;
        float4 v = kgp[fi];
        union { f16 h[4]; uint2 u; } c;
        c.h[0]=(f16)v.x; c.h[1]=(f16)v.y; c.h[2]=(f16)v.z; c.h[3]=(f16)v.w;
        int off = krow * 256 + ((d4 * 8) ^ ((krow & 7) << 4));
        *(uint2*)((char*)K_lds + off) = c.u;
      }
    }
    {
      const float* vgp = Vg + hbase + (size_t)k0 * DIM;
#pragma unroll
      for (int rr = 0; rr < 16; ++rr) {
        int u = rr * 256 + tid;
        int d = u & 127;
        int k2 = (u >> 7) * 2;
        float v0 = vgp[(size_t)k2 * DIM + d];
        float v1 = vgp[(size_t)(k2 + 1) * DIM + d];
        union { f16 h[2]; unsigned int u32; } c;
        c.h[0]=(f16)v0; c.h[1]=(f16)v1;
        *(unsigned int*)(Vt_lds + d * VT_STRIDE + k2) = c.u32;
      }
    }
    if (tid < KVBLK) M_lds[tid] = Mg[(size_t)bb * SEQ + k0 + tid];
    __syncthreads();
    f32x4 sacc[4];
#pragma unroll
    for (int kt = 0; kt < 4; ++kt) sacc[kt] = (f32x4)(0.f);
#pragma unroll
    for (int kt = 0; kt < 4; ++kt) {
      const int krow = kt * 16 + li;
      const int swz = (krow & 7) << 4;
#pragma unroll
      for (int d0 = 0; d0 < 4; ++d0) {
        f16x8 kf = *(const f16x8*)((const char*)K_lds + krow * 256 + ((d0 * 64 + g * 16) ^ swz));
        sacc[kt] = __builtin_amdgcn_mfma_f32_16x16x32_f16(qf[d0], kf, sacc[kt], 0, 0, 0);
      }
    }
    float tmax[4] = {-INFINITY, -INFINITY, -INFINITY, -INFINITY};
#pragma unroll
    for (int kt = 0; kt < 4; ++kt) {
      const bool ok = (M_lds[kt * 16 + li] != 0);
#pragma unroll
      for (int r = 0; r < 4; ++r) {
        float sv = ok ? sacc[kt][r] : -1e9f;
        sacc[kt][r] = sv;
        tmax[r] = fmaxf(tmax[r], sv);
      }
    }
#pragma unroll
    for (int r = 0; r < 4; ++r) {
      tmax[r] = fmaxf(tmax[r], __shfl_xor(tmax[r], 1));
      tmax[r] = fmaxf(tmax[r], __shfl_xor(tmax[r], 2));
      tmax[r] = fmaxf(tmax[r], __shfl_xor(tmax[r], 4));
      tmax[r] = fmaxf(tmax[r], __shfl_xor(tmax[r], 8));
    }
    float sc[4], psum[4];
#pragma unroll
    for (int r = 0; r < 4; ++r) {
      float mnew = fmaxf(mrow[r], tmax[r]);
      sc[r] = __expf(mrow[r] - mnew);
      mrow[r] = mnew;
      psum[r] = 0.f;
    }
#pragma unroll
    for (int dt = 0; dt < 8; ++dt)
#pragma unroll
      for (int r = 0; r < 4; ++r) oacc[dt][r] *= sc[r];
#pragma unroll
    for (int kt = 0; kt < 4; ++kt) {
#pragma unroll
      for (int r = 0; r < 4; ++r) {
        float p = __expf(sacc[kt][r] - mrow[r]);
        psum[r] += p;
        P_lds[(w * 16 + g * 4 + r) * P_STRIDE + kt * 16 + li] =
            __builtin_bit_cast(ushort_t, (f16)p);
      }
    }
#pragma unroll
    for (int r = 0; r < 4; ++r) {
      psum[r] += __shfl_xor(psum[r], 1);
      psum[r] += __shfl_xor(psum[r], 2);
      psum[r] += __shfl_xor(psum[r], 4);
      psum[r] += __shfl_xor(psum[r], 8);
      lrow[r] = lrow[r] * sc[r] + psum[r];
    }
#pragma unroll
    for (int c = 0; c < 2; ++c) {
      f16x8 pa = *(const f16x8*)(P_lds + (w * 16 + li) * P_STRIDE + c * 32 + g * 8);
#pragma unroll
      for (int dt = 0; dt < 8; ++dt) {
        const ushort_t* vp = Vt_lds + (dt * 16 + li) * VT_STRIDE + c * 32 + g * 8;
        f16x4_t v0 = *(const f16x4_t*)vp;
        f16x4_t v1 = *(const f16x4_t*)(vp + 4);
        f16x8 vf;
        vf[0]=v0[0]; vf[1]=v0[1]; vf[2]=v0[2]; vf[3]=v0[3];
        vf[4]=v1[0]; vf[5]=v1[1]; vf[6]=v1[2]; vf[7]=v1[3];
        oacc[dt] = __builtin_amdgcn_mfma_f32_16x16x32_f16(pa, vf, oacc[dt], 0, 0, 0);
      }
    }
  }
#pragma unroll
  for (int r = 0; r < 4; ++r) {
    float inv = 1.0f / lrow[r];
    float* op = Og + hbase + (size_t)(qblk * QT + w * 16 + g * 4 + r) * DIM + li;
#pragma unroll
    for (int dt = 0; dt < 8; ++dt) op[dt * 16] = oacc[dt][r] * inv;
  }
}

extern "C" void kernel_launch(void* const* d_in, const int* in_sizes, int n_in,
                              void* d_out, int out_size, void* d_ws, size_t ws_size,
                              hipStream_t stream) {
  (void)in_sizes; (void)n_in; (void)out_size;
  const float* Q = (const float*)d_in[0];
  const float* K = (const float*)d_in[1];
  const float* V = (const float*)d_in[2];
  const int*   M = (const int*)d_in[3];
  float*       O = (float*)d_out;

  const size_t half = (size_t)2048 * TILE_BYTES;   // 33.5 MB each
  if (ws_size >= 2 * half) {
    char* Kws = (char*)d_ws;
    char* Vws = Kws + half;
    prep_k<<<dim3(2048), dim3(256), 0, stream>>>(K, Kws);
    prep_v<<<dim3(2048), dim3(256), 0, stream>>>(V, Vws);
    attn_main32<<<dim3(512), dim3(512), 0, stream>>>(Q, Kws, Vws, M, O);
  } else {
    attn_fwd_fb<<<dim3(2048), dim3(256), 0, stream>>>(Q, K, V, M, O);
  }
}

// Round 5
// 143.913 us; speedup vs baseline: 2.7414x; 1.4622x over previous
//
#include <hip/hip_runtime.h>

typedef _Float16 f16;
typedef _Float16 f16x8 __attribute__((ext_vector_type(8)));
typedef _Float16 f16x4 __attribute__((ext_vector_type(4)));
typedef float f32x4 __attribute__((ext_vector_type(4)));
typedef float f32x16 __attribute__((ext_vector_type(16)));
typedef unsigned short ushort_t;
typedef unsigned int uint_t;

#define SEQ 2048
#define DIM 128
#define KVBLK 64
#define NTMAX (SEQ / KVBLK)   // 32 k-tiles max
#define TILE_BYTES 16384      // 64x128 (or 128x64) f16 tile image

typedef __attribute__((address_space(3))) char lds_char;
typedef __attribute__((address_space(1))) const char glb_char;

__device__ __forceinline__ void gload16(const void* g, void* l) {
  __builtin_amdgcn_global_load_lds((glb_char*)g, (lds_char*)l, 16, 0, 0);
}

// ---------------- scan: per-batch compaction of unmasked key indices ----------------
// 1 wave per batch; deterministic (no atomics). cidx[b][j] = orig idx of j-th unmasked key.
__global__ __launch_bounds__(64)
void scan_mask(const int* __restrict__ Mg, int* __restrict__ cidx, int* __restrict__ ncomp) {
  const int b = blockIdx.x;
  const int l = threadIdx.x;          // 0..63
  int m[32];
  int cnt = 0;
  const int* mp = Mg + (size_t)b * SEQ + l * 32;
#pragma unroll
  for (int j = 0; j < 32; ++j) { m[j] = mp[j]; cnt += (m[j] != 0) ? 1 : 0; }
  int inc = cnt;
  for (int ofs = 1; ofs < 64; ofs <<= 1) {
    int v = __shfl_up(inc, ofs);
    if (l >= ofs) inc += v;
  }
  int pos = inc - cnt;                // exclusive prefix
  int* cp = cidx + (size_t)b * SEQ;
  for (int j = 0; j < 32; ++j)
    if (m[j] != 0) cp[pos++] = l * 32 + j;
  if (l == 63) ncomp[b] = inc;
}

// ---------------- pre-pass: gathered K -> f16, swizzled 64x128 tile images ----------------
// f16 (krow,d) -> byte  krow*256 + (((d>>3) ^ (krow&7))<<4) + (d&7)*2   [verified R3/R4]
__global__ __launch_bounds__(256)
void prep_k(const float* __restrict__ Kg, char* __restrict__ Kws,
            const int* __restrict__ cidx, const int* __restrict__ ncomp) {
  const int tid  = threadIdx.x;
  const int blk  = blockIdx.x;        // head*32 + t
  const int head = blk >> 5, t = blk & 31;
  const int b    = head >> 4;
  const int nc   = ncomp[b];
  if (t >= ((nc + 63) >> 6)) return;
  const float* hin = Kg + (size_t)head * SEQ * DIM;
  const int* cp = cidx + (size_t)b * SEQ;
  char* out = Kws + (size_t)blk * TILE_BYTES;
#pragma unroll
  for (int i = 0; i < 4; ++i) {
    int u = i * 256 + tid;
    int krow = u >> 4;
    int un   = u & 15;
    int kidx = t * 64 + krow;
    union { f16 h[8]; uint4 u4; } c;
    if (kidx < nc) {
      const float* p = hin + (size_t)cp[kidx] * DIM + un * 8;
      float4 a = *(const float4*)p;
      float4 bq = *(const float4*)(p + 4);
      c.h[0]=(f16)a.x;  c.h[1]=(f16)a.y;  c.h[2]=(f16)a.z;  c.h[3]=(f16)a.w;
      c.h[4]=(f16)bq.x; c.h[5]=(f16)bq.y; c.h[6]=(f16)bq.z; c.h[7]=(f16)bq.w;
    } else {
      c.u4 = uint4{0, 0, 0, 0};
    }
    *(uint4*)(out + krow * 256 + ((un ^ (krow & 7)) << 4)) = c.u4;
  }
}

// ---------------- pre-pass: gathered V -> f16 transposed, swizzled 128x64 tiles ----------------
// f16 (k,dv) -> byte  dv*128 + (((k>>3) ^ (dv&7))<<4) + (k&7)*2   [verified R3/R4]
__global__ __launch_bounds__(256)
void prep_v(const float* __restrict__ Vg, char* __restrict__ Vws,
            const int* __restrict__ cidx, const int* __restrict__ ncomp) {
  __shared__ ushort_t Vs[KVBLK * 133];
  const int tid  = threadIdx.x;
  const int blk  = blockIdx.x;
  const int head = blk >> 5, t = blk & 31;
  const int b    = head >> 4;
  const int nc   = ncomp[b];
  if (t >= ((nc + 63) >> 6)) return;
  const float* hin = Vg + (size_t)head * SEQ * DIM;
  const int* cp = cidx + (size_t)b * SEQ;
  char* out = Vws + (size_t)blk * TILE_BYTES;
#pragma unroll
  for (int i = 0; i < 4; ++i) {
    int u = i * 256 + tid;
    int k  = u >> 4;
    int d0 = (u & 15) * 8;
    int kidx = t * 64 + k;
    f16 h[8];
    if (kidx < nc) {
      const float* p = hin + (size_t)cp[kidx] * DIM + d0;
      float4 a = *(const float4*)p;
      float4 bq = *(const float4*)(p + 4);
      h[0]=(f16)a.x;  h[1]=(f16)a.y;  h[2]=(f16)a.z;  h[3]=(f16)a.w;
      h[4]=(f16)bq.x; h[5]=(f16)bq.y; h[6]=(f16)bq.z; h[7]=(f16)bq.w;
    } else {
#pragma unroll
      for (int j = 0; j < 8; ++j) h[j] = (f16)0.f;
    }
#pragma unroll
    for (int j = 0; j < 8; ++j)
      Vs[k * 133 + d0 + j] = __builtin_bit_cast(ushort_t, h[j]);
  }
  __syncthreads();
#pragma unroll
  for (int i = 0; i < 4; ++i) {
    int u = i * 256 + tid;
    int d  = u >> 3;
    int un = u & 7;
    union { f16 h[8]; uint4 u4; } c;
#pragma unroll
    for (int j = 0; j < 8; ++j)
      c.h[j] = __builtin_bit_cast(f16, Vs[(un * 8 + j) * 133 + d]);
    *(uint4*)(out + d * 128 + ((un ^ (d & 7)) << 4)) = c.u4;
  }
}

// ---------------- main: 8 waves x QBLK32, 32x32x16 MFMA, swapped QK^T & PV, compacted K ----------------
__global__ __launch_bounds__(512, 2)
void attn_main32(const float* __restrict__ Qg, const char* __restrict__ Kws,
                 const char* __restrict__ Vws, const int* __restrict__ ncomp,
                 float* __restrict__ Og) {
  __shared__ __align__(16) char Kb[2][TILE_BYTES];
  __shared__ __align__(16) char Vb[2][TILE_BYTES];

  const int tid  = threadIdx.x;
  const int lane = tid & 63;
  const int w    = tid >> 6;       // wave 0..7
  const int q32  = lane & 31;
  const int h    = lane >> 5;

  // XCD grouping: same-XCD blocks share 8 heads' compacted K/V
  const int bid  = blockIdx.x;                  // 0..511
  const int head = (bid & 7) * 8 + (bid >> 6);  // 0..63
  const int qblk = (bid >> 3) & 7;              // 0..7
  const size_t hbase = (size_t)head * SEQ * DIM;
  const int bb = head >> 4;

  const int nc  = ncomp[bb];
  const int ntb = (nc + 63) >> 6;               // >=1 for this input

  const char* ktb = Kws + ((size_t)(head * NTMAX) << 14);
  const char* vtb = Vws + ((size_t)(head * NTMAX) << 14);

  const int qrow = qblk * 256 + w * 32 + q32;

  // Q fragments: lane holds Q[qrow][d = 16c + 8h + j], j=0..7
  f16x8 qf[8];
  {
    const float* qp = Qg + hbase + (size_t)qrow * DIM + h * 8;
#pragma unroll
    for (int c = 0; c < 8; ++c) {
      float4 a = *(const float4*)(qp + c * 16);
      float4 b = *(const float4*)(qp + c * 16 + 4);
      f16x8 f;
      f[0]=(f16)a.x; f[1]=(f16)a.y; f[2]=(f16)a.z; f[3]=(f16)a.w;
      f[4]=(f16)b.x; f[5]=(f16)b.y; f[6]=(f16)b.z; f[7]=(f16)b.w;
      qf[c] = f;
    }
  }

  f32x16 oacc[4];
#pragma unroll
  for (int dvt = 0; dvt < 4; ++dvt) oacc[dvt] = (f32x16)(0.f);
  float mrow = -INFINITY, lrow = 0.f;

  // prologue: stage tile 0
  {
#pragma unroll
    for (int i = 0; i < 2; ++i) {
      int u = i * 512 + tid;
      gload16(ktb + u * 16, &Kb[0][u * 16]);
      gload16(vtb + u * 16, &Vb[0][u * 16]);
    }
  }
  __syncthreads();

  int cur = 0;
  for (int t = 0; t < ntb; ++t) {
    // issue next tile staging (overlaps with compute)
    if (t + 1 < ntb) {
      const char* kt2 = ktb + ((size_t)(t + 1) << 14);
      const char* vt2 = vtb + ((size_t)(t + 1) << 14);
      const int nb = cur ^ 1;
#pragma unroll
      for (int i = 0; i < 2; ++i) {
        int u = i * 512 + tid;
        gload16(kt2 + u * 16, &Kb[nb][u * 16]);
        gload16(vt2 + u * 16, &Vb[nb][u * 16]);
      }
    }

    // ---- QK^T (swapped): lane holds S[q=q32][k = t*64 + kt2*32 + crow(r,h)] ----
    // crow(ri,h) = (ri>>2)*8 + 4h + (ri&3)
    f32x16 s[2];
#pragma unroll
    for (int kt2 = 0; kt2 < 2; ++kt2) {
      const int kb = t * 64 + kt2 * 32;
      if (kb + 32 <= nc) {
        s[kt2] = (f32x16)(0.f);
      } else {
#pragma unroll
        for (int ri = 0; ri < 16; ++ri)
          s[kt2][ri] = (kb + (ri >> 2) * 8 + 4 * h + (ri & 3) < nc) ? 0.f : -1e9f;
      }
      const int krow = kt2 * 32 + q32;
      const int ksw  = krow & 7;
      __builtin_amdgcn_s_setprio(1);
#pragma unroll
      for (int c = 0; c < 8; ++c) {
        f16x8 kf = *(const f16x8*)(&Kb[cur][krow * 256 + (((2 * c + h) ^ ksw) << 4)]);
        s[kt2] = __builtin_amdgcn_mfma_f32_32x32x16_f16(kf, qf[c], s[kt2], 0, 0, 0);
      }
      __builtin_amdgcn_s_setprio(0);
    }

    // ---- online softmax (lane-local row) ----
    float pmax = s[0][0];
#pragma unroll
    for (int r = 1; r < 16; ++r) pmax = fmaxf(pmax, s[0][r]);
#pragma unroll
    for (int r = 0; r < 16; ++r) pmax = fmaxf(pmax, s[1][r]);
    pmax = fmaxf(pmax, __shfl_xor(pmax, 32));

    if (!__all(pmax - mrow <= 8.f)) {          // defer-max (T13)
      float mnew = fmaxf(mrow, pmax);
      float scf = __expf(mrow - mnew);
#pragma unroll
      for (int dvt = 0; dvt < 4; ++dvt)
#pragma unroll
        for (int r = 0; r < 16; ++r) oacc[dvt][r] *= scf;
      lrow *= scf;
      mrow = mnew;
    }

    float psum = 0.f;
#pragma unroll
    for (int t2 = 0; t2 < 2; ++t2)
#pragma unroll
      for (int r = 0; r < 16; ++r) {
        float p = __expf(s[t2][r] - mrow);
        s[t2][r] = p;
        psum += p;
      }
    psum += __shfl_xor(psum, 32);
    lrow += psum;

    // ---- pack P to f16 pairs ----
    uint_t pkA[2][4], pkB[2][4];
#pragma unroll
    for (int t2 = 0; t2 < 2; ++t2)
#pragma unroll
      for (int m = 0; m < 4; ++m) {
        pkA[t2][m] = __builtin_bit_cast(uint_t,
            __builtin_amdgcn_cvt_pkrtz(s[t2][4 * m + 0], s[t2][4 * m + 1]));
        pkB[t2][m] = __builtin_bit_cast(uint_t,
            __builtin_amdgcn_cvt_pkrtz(s[t2][4 * m + 2], s[t2][4 * m + 3]));
      }

    // ---- PV (swapped): O^T += V^T * P^T ; pa[j] = P[q32][16ks+8h+j] ----
#pragma unroll
    for (int ks = 0; ks < 4; ++ks) {
      const int sk = ks & 1, tt = ks >> 1;
      uint_t Ao = h ? pkA[tt][2 * sk + 1] : pkA[tt][2 * sk];
      uint_t Bo = h ? pkB[tt][2 * sk + 1] : pkB[tt][2 * sk];
      uint_t As = h ? pkA[tt][2 * sk]     : pkA[tt][2 * sk + 1];
      uint_t Bs = h ? pkB[tt][2 * sk]     : pkB[tt][2 * sk + 1];
      uint_t Ax = (uint_t)__shfl_xor((int)As, 32);
      uint_t Bx = (uint_t)__shfl_xor((int)Bs, 32);
      union { uint_t u[4]; f16x8 v; } pa;
      pa.u[0] = h ? Ax : Ao;
      pa.u[1] = h ? Bx : Bo;
      pa.u[2] = h ? Ao : Ax;
      pa.u[3] = h ? Bo : Bx;
      __builtin_amdgcn_s_setprio(1);
#pragma unroll
      for (int dvt = 0; dvt < 4; ++dvt) {
        const int dv = dvt * 32 + q32;
        f16x8 vf = *(const f16x8*)(&Vb[cur][dv * 128 + (((2 * ks + h) ^ (dv & 7)) << 4)]);
        oacc[dvt] = __builtin_amdgcn_mfma_f32_32x32x16_f16(vf, pa.v, oacc[dvt], 0, 0, 0);
      }
      __builtin_amdgcn_s_setprio(0);
    }

    __syncthreads();
    cur ^= 1;
  }

  // ---- epilogue ----
  const float inv = 1.0f / lrow;
  float* op = Og + hbase + (size_t)qrow * DIM;
#pragma unroll
  for (int dvt = 0; dvt < 4; ++dvt)
#pragma unroll
    for (int rq = 0; rq < 4; ++rq) {
      float4 o4;
      o4.x = oacc[dvt][4 * rq + 0] * inv;
      o4.y = oacc[dvt][4 * rq + 1] * inv;
      o4.z = oacc[dvt][4 * rq + 2] * inv;
      o4.w = oacc[dvt][4 * rq + 3] * inv;
      *(float4*)(op + dvt * 32 + rq * 8 + h * 4) = o4;
    }
}

// ---------------- fallback (verified round-1 kernel) for small ws ----------------
#define QT 64
#define P_STRIDE 72
#define VT_STRIDE 76
typedef _Float16 f16x4_t __attribute__((ext_vector_type(4)));
__global__ __launch_bounds__(256, 2)
void attn_fwd_fb(const float* __restrict__ Qg, const float* __restrict__ Kg,
                 const float* __restrict__ Vg, const int* __restrict__ Mg,
                 float* __restrict__ Og) {
  __shared__ __align__(16) ushort_t K_lds[QT * DIM];
  __shared__ __align__(16) ushort_t Vt_lds[DIM * VT_STRIDE];
  __shared__ __align__(16) ushort_t P_lds[QT * P_STRIDE];
  __shared__ int M_lds[KVBLK];
  const int tid  = threadIdx.x;
  const int lane = tid & 63;
  const int w    = tid >> 6;
  const int li   = lane & 15;
  const int g    = lane >> 4;
  const int bid  = blockIdx.x;
  const int nid  = (bid & 7) * 256 + (bid >> 3);
  const int head = nid >> 5;
  const int qblk = nid & 31;
  const size_t hbase = (size_t)head * SEQ * DIM;
  const int bb = head >> 4;
  f16x8 qf[4];
  {
    const float* qp = Qg + hbase + (size_t)(qblk * QT + w * 16 + li) * DIM + g * 8;
#pragma unroll
    for (int d0 = 0; d0 < 4; ++d0) {
      float4 a = *(const float4*)(qp + d0 * 32);
      float4 b = *(const float4*)(qp + d0 * 32 + 4);
      f16x8 f;
      f[0]=(f16)a.x; f[1]=(f16)a.y; f[2]=(f16)a.z; f[3]=(f16)a.w;
      f[4]=(f16)b.x; f[5]=(f16)b.y; f[6]=(f16)b.z; f[7]=(f16)b.w;
      qf[d0] = f;
    }
  }
  float mrow[4], lrow[4];
  f32x4 oacc[8];
#pragma unroll
  for (int r = 0; r < 4; ++r) { mrow[r] = -INFINITY; lrow[r] = 0.f; }
#pragma unroll
  for (int dt = 0; dt < 8; ++dt) oacc[dt] = (f32x4)(0.f);
  for (int t = 0; t < NTMAX; ++t) {
    const int k0 = t * KVBLK;
    __syncthreads();
    {
      const float4* kgp = (const float4*)(Kg + hbase + (size_t)k0 * DIM);
#pragma unroll
      for (int rr = 0; rr < 8; ++rr) {
        int fi = rr * 256 + tid;
        int krow = fi >> 5;
        int d4 = fi & 31;
        float4 v = kgp[fi];
        union { f16 h[4]; uint2 u; } c;
        c.h[0]=(f16)v.x; c.h[1]=(f16)v.y; c.h[2]=(f16)v.z; c.h[3]=(f16)v.w;
        int off = krow * 256 + ((d4 * 8) ^ ((krow & 7) << 4));
        *(uint2*)((char*)K_lds + off) = c.u;
      }
    }
    {
      const float* vgp = Vg + hbase + (size_t)k0 * DIM;
#pragma unroll
      for (int rr = 0; rr < 16; ++rr) {
        int u = rr * 256 + tid;
        int d = u & 127;
        int k2 = (u >> 7) * 2;
        float v0 = vgp[(size_t)k2 * DIM + d];
        float v1 = vgp[(size_t)(k2 + 1) * DIM + d];
        union { f16 h[2]; unsigned int u32; } c;
        c.h[0]=(f16)v0; c.h[1]=(f16)v1;
        *(unsigned int*)(Vt_lds + d * VT_STRIDE + k2) = c.u32;
      }
    }
    if (tid < KVBLK) M_lds[tid] = Mg[(size_t)bb * SEQ + k0 + tid];
    __syncthreads();
    f32x4 sacc[4];
#pragma unroll
    for (int kt = 0; kt < 4; ++kt) sacc[kt] = (f32x4)(0.f);
#pragma unroll
    for (int kt = 0; kt < 4; ++kt) {
      const int krow = kt * 16 + li;
      const int swz = (krow & 7) << 4;
#pragma unroll
      for (int d0 = 0; d0 < 4; ++d0) {
        f16x8 kf = *(const f16x8*)((const char*)K_lds + krow * 256 + ((d0 * 64 + g * 16) ^ swz));
        sacc[kt] = __builtin_amdgcn_mfma_f32_16x16x32_f16(qf[d0], kf, sacc[kt], 0, 0, 0);
      }
    }
    float tmax[4] = {-INFINITY, -INFINITY, -INFINITY, -INFINITY};
#pragma unroll
    for (int kt = 0; kt < 4; ++kt) {
      const bool ok = (M_lds[kt * 16 + li] != 0);
#pragma unroll
      for (int r = 0; r < 4; ++r) {
        float sv = ok ? sacc[kt][r] : -1e9f;
        sacc[kt][r] = sv;
        tmax[r] = fmaxf(tmax[r], sv);
      }
    }
#pragma unroll
    for (int r = 0; r < 4; ++r) {
      tmax[r] = fmaxf(tmax[r], __shfl_xor(tmax[r], 1));
      tmax[r] = fmaxf(tmax[r], __shfl_xor(tmax[r], 2));
      tmax[r] = fmaxf(tmax[r], __shfl_xor(tmax[r], 4));
      tmax[r] = fmaxf(tmax[r], __shfl_xor(tmax[r], 8));
    }
    float sc[4], psum[4];
#pragma unroll
    for (int r = 0; r < 4; ++r) {
      float mnew = fmaxf(mrow[r], tmax[r]);
      sc[r] = __expf(mrow[r] - mnew);
      mrow[r] = mnew;
      psum[r] = 0.f;
    }
#pragma unroll
    for (int dt = 0; dt < 8; ++dt)
#pragma unroll
      for (int r = 0; r < 4; ++r) oacc[dt][r] *= sc[r];
#pragma unroll
    for (int kt = 0; kt < 4; ++kt) {
#pragma unroll
      for (int r = 0; r < 4; ++r) {
        float p = __expf(sacc[kt][r] - mrow[r]);
        psum[r] += p;
        P_lds[(w * 16 + g * 4 + r) * P_STRIDE + kt * 16 + li] =
            __builtin_bit_cast(ushort_t, (f16)p);
      }
    }
#pragma unroll
    for (int r = 0; r < 4; ++r) {
      psum[r] += __shfl_xor(psum[r], 1);
      psum[r] += __shfl_xor(psum[r], 2);
      psum[r] += __shfl_xor(psum[r], 4);
      psum[r] += __shfl_xor(psum[r], 8);
      lrow[r] = lrow[r] * sc[r] + psum[r];
    }
#pragma unroll
    for (int c = 0; c < 2; ++c) {
      f16x8 pa = *(const f16x8*)(P_lds + (w * 16 + li) * P_STRIDE + c * 32 + g * 8);
#pragma unroll
      for (int dt = 0; dt < 8; ++dt) {
        const ushort_t* vp = Vt_lds + (dt * 16 + li) * VT_STRIDE + c * 32 + g * 8;
        f16x4_t v0 = *(const f16x4_t*)vp;
        f16x4_t v1 = *(const f16x4_t*)(vp + 4);
        f16x8 vf;
        vf[0]=v0[0]; vf[1]=v0[1]; vf[2]=v0[2]; vf[3]=v0[3];
        vf[4]=v1[0]; vf[5]=v1[1]; vf[6]=v1[2]; vf[7]=v1[3];
        oacc[dt] = __builtin_amdgcn_mfma_f32_16x16x32_f16(pa, vf, oacc[dt], 0, 0, 0);
      }
    }
  }
#pragma unroll
  for (int r = 0; r < 4; ++r) {
    float inv = 1.0f / lrow[r];
    float* op = Og + hbase + (size_t)(qblk * QT + w * 16 + g * 4 + r) * DIM + li;
#pragma unroll
    for (int dt = 0; dt < 8; ++dt) op[dt * 16] = oacc[dt][r] * inv;
  }
}

extern "C" void kernel_launch(void* const* d_in, const int* in_sizes, int n_in,
                              void* d_out, int out_size, void* d_ws, size_t ws_size,
                              hipStream_t stream) {
  (void)in_sizes; (void)n_in; (void)out_size;
  const float* Q = (const float*)d_in[0];
  const float* K = (const float*)d_in[1];
  const float* V = (const float*)d_in[2];
  const int*   M = (const int*)d_in[3];
  float*       O = (float*)d_out;

  const size_t half = (size_t)2048 * TILE_BYTES;         // 33.5 MB each
  const size_t cidx_off  = 2 * half;
  const size_t ncomp_off = cidx_off + (size_t)4 * SEQ * sizeof(int);
  const size_t need = ncomp_off + 4 * sizeof(int);

  if (ws_size >= need) {
    char* Kws = (char*)d_ws;
    char* Vws = Kws + half;
    int*  cidx  = (int*)((char*)d_ws + cidx_off);
    int*  ncomp = (int*)((char*)d_ws + ncomp_off);
    scan_mask<<<dim3(4), dim3(64), 0, stream>>>(M, cidx, ncomp);
    prep_k<<<dim3(2048), dim3(256), 0, stream>>>(K, Kws, cidx, ncomp);
    prep_v<<<dim3(2048), dim3(256), 0, stream>>>(V, Vws, cidx, ncomp);
    attn_main32<<<dim3(512), dim3(512), 0, stream>>>(Q, Kws, Vws, ncomp, O);
  } else {
    attn_fwd_fb<<<dim3(2048), dim3(256), 0, stream>>>(Q, K, V, M, O);
  }
}

// Round 6
// 143.582 us; speedup vs baseline: 2.7477x; 1.0023x over previous
//
#include <hip/hip_runtime.h>

typedef _Float16 f16;
typedef _Float16 f16x8 __attribute__((ext_vector_type(8)));
typedef _Float16 f16x4 __attribute__((ext_vector_type(4)));
typedef float f32x4 __attribute__((ext_vector_type(4)));
typedef float f32x16 __attribute__((ext_vector_type(16)));
typedef unsigned short ushort_t;
typedef unsigned int uint_t;

#define SEQ 2048
#define DIM 128
#define KVBLK 64
#define NTMAX (SEQ / KVBLK)   // 32 k-tiles max
#define TILE_BYTES 16384      // 64x128 (or 128x64) f16 tile image

typedef __attribute__((address_space(3))) char lds_char;
typedef __attribute__((address_space(1))) const char glb_char;

__device__ __forceinline__ void gload16(const void* g, void* l) {
  __builtin_amdgcn_global_load_lds((glb_char*)g, (lds_char*)l, 16, 0, 0);
}

// ---------------- scan: per-batch compaction of unmasked key indices ----------------
__global__ __launch_bounds__(64)
void scan_mask(const int* __restrict__ Mg, int* __restrict__ cidx, int* __restrict__ ncomp) {
  const int b = blockIdx.x;
  const int l = threadIdx.x;
  int m[32];
  int cnt = 0;
  const int* mp = Mg + (size_t)b * SEQ + l * 32;
#pragma unroll
  for (int j = 0; j < 32; ++j) { m[j] = mp[j]; cnt += (m[j] != 0) ? 1 : 0; }
  int inc = cnt;
  for (int ofs = 1; ofs < 64; ofs <<= 1) {
    int v = __shfl_up(inc, ofs);
    if (l >= ofs) inc += v;
  }
  int pos = inc - cnt;
  int* cp = cidx + (size_t)b * SEQ;
  for (int j = 0; j < 32; ++j)
    if (m[j] != 0) cp[pos++] = l * 32 + j;
  if (l == 63) ncomp[b] = inc;
}

// ---------------- pre-pass: gathered K -> f16, swizzled 64x128 tile images ----------------
// f16 (krow,d) -> byte  krow*256 + (((d>>3) ^ (krow&15))<<4) + (d&7)*2   [&15: 2-way max]
__global__ __launch_bounds__(256)
void prep_k(const float* __restrict__ Kg, char* __restrict__ Kws,
            const int* __restrict__ cidx, const int* __restrict__ ncomp) {
  const int tid  = threadIdx.x;
  const int blk  = blockIdx.x;        // head*32 + t
  const int head = blk >> 5, t = blk & 31;
  const int b    = head >> 4;
  const int nc   = ncomp[b];
  if (t >= ((nc + 63) >> 6)) return;
  const float* hin = Kg + (size_t)head * SEQ * DIM;
  const int* cp = cidx + (size_t)b * SEQ;
  char* out = Kws + (size_t)blk * TILE_BYTES;
#pragma unroll
  for (int i = 0; i < 4; ++i) {
    int u = i * 256 + tid;
    int krow = u >> 4;
    int un   = u & 15;
    int kidx = t * 64 + krow;
    union { f16 h[8]; uint4 u4; } c;
    if (kidx < nc) {
      const float* p = hin + (size_t)cp[kidx] * DIM + un * 8;
      float4 a = *(const float4*)p;
      float4 bq = *(const float4*)(p + 4);
      c.h[0]=(f16)a.x;  c.h[1]=(f16)a.y;  c.h[2]=(f16)a.z;  c.h[3]=(f16)a.w;
      c.h[4]=(f16)bq.x; c.h[5]=(f16)bq.y; c.h[6]=(f16)bq.z; c.h[7]=(f16)bq.w;
    } else {
      c.u4 = uint4{0, 0, 0, 0};
    }
    *(uint4*)(out + krow * 256 + ((un ^ (krow & 15)) << 4)) = c.u4;
  }
}

// ---------------- pre-pass: gathered V -> f16 transposed, swizzled 128x64 tiles ----------------
// f16 (k,dv) -> byte  dv*128 + (((k>>3) ^ (dv&7))<<4) + (k&7)*2   [verified R3/R4]
__global__ __launch_bounds__(256)
void prep_v(const float* __restrict__ Vg, char* __restrict__ Vws,
            const int* __restrict__ cidx, const int* __restrict__ ncomp) {
  __shared__ ushort_t Vs[KVBLK * 133];
  const int tid  = threadIdx.x;
  const int blk  = blockIdx.x;
  const int head = blk >> 5, t = blk & 31;
  const int b    = head >> 4;
  const int nc   = ncomp[b];
  if (t >= ((nc + 63) >> 6)) return;
  const float* hin = Vg + (size_t)head * SEQ * DIM;
  const int* cp = cidx + (size_t)b * SEQ;
  char* out = Vws + (size_t)blk * TILE_BYTES;
#pragma unroll
  for (int i = 0; i < 4; ++i) {
    int u = i * 256 + tid;
    int k  = u >> 4;
    int d0 = (u & 15) * 8;
    int kidx = t * 64 + k;
    f16 h[8];
    if (kidx < nc) {
      const float* p = hin + (size_t)cp[kidx] * DIM + d0;
      float4 a = *(const float4*)p;
      float4 bq = *(const float4*)(p + 4);
      h[0]=(f16)a.x;  h[1]=(f16)a.y;  h[2]=(f16)a.z;  h[3]=(f16)a.w;
      h[4]=(f16)bq.x; h[5]=(f16)bq.y; h[6]=(f16)bq.z; h[7]=(f16)bq.w;
    } else {
#pragma unroll
      for (int j = 0; j < 8; ++j) h[j] = (f16)0.f;
    }
#pragma unroll
    for (int j = 0; j < 8; ++j)
      Vs[k * 133 + d0 + j] = __builtin_bit_cast(ushort_t, h[j]);
  }
  __syncthreads();
#pragma unroll
  for (int i = 0; i < 4; ++i) {
    int u = i * 256 + tid;
    int d  = u >> 3;
    int un = u & 7;
    union { f16 h[8]; uint4 u4; } c;
#pragma unroll
    for (int j = 0; j < 8; ++j)
      c.h[j] = __builtin_bit_cast(f16, Vs[(un * 8 + j) * 133 + d]);
    *(uint4*)(out + d * 128 + ((un ^ (d & 7)) << 4)) = c.u4;
  }
}

// ---------------- main: 8 waves x QBLK32, counted-vmcnt pipeline (T4) ----------------
__global__ __launch_bounds__(512, 2)
void attn_main32(const float* __restrict__ Qg, const char* __restrict__ Kws,
                 const char* __restrict__ Vws, const int* __restrict__ ncomp,
                 float* __restrict__ Og) {
  __shared__ __align__(16) char Kb[2][TILE_BYTES];
  __shared__ __align__(16) char Vb[2][TILE_BYTES];

  const int tid  = threadIdx.x;
  const int lane = tid & 63;
  const int q32  = lane & 31;
  const int h    = lane >> 5;
  const int w    = tid >> 6;
  (void)w;

  const int bid  = blockIdx.x;                  // 0..511
  const int head = (bid & 7) * 8 + (bid >> 6);  // XCD grouping
  const int qblk = (bid >> 3) & 7;
  const size_t hbase = (size_t)head * SEQ * DIM;
  const int bb = head >> 4;

  const int nc  = ncomp[bb];
  const int ntb = (nc + 63) >> 6;

  const char* ktb = Kws + ((size_t)(head * NTMAX) << 14);
  const char* vtb = Vws + ((size_t)(head * NTMAX) << 14);

  const int qrow = qblk * 256 + (tid >> 6) * 32 + q32;

  // Q fragments: lane holds Q[qrow][d = 16c + 8h + j]
  f16x8 qf[8];
  {
    const float* qp = Qg + hbase + (size_t)qrow * DIM + h * 8;
#pragma unroll
    for (int c = 0; c < 8; ++c) {
      float4 a = *(const float4*)(qp + c * 16);
      float4 b = *(const float4*)(qp + c * 16 + 4);
      f16x8 f;
      f[0]=(f16)a.x; f[1]=(f16)a.y; f[2]=(f16)a.z; f[3]=(f16)a.w;
      f[4]=(f16)b.x; f[5]=(f16)b.y; f[6]=(f16)b.z; f[7]=(f16)b.w;
      qf[c] = f;
    }
  }

  f32x16 oacc[4];
#pragma unroll
  for (int dvt = 0; dvt < 4; ++dvt) oacc[dvt] = (f32x16)(0.f);
  float mrow = -INFINITY, lrow = 0.f;

  // prologue: issue tile-0 staging (no barrier; loop head waits)
#pragma unroll
  for (int i = 0; i < 2; ++i) {
    int u = i * 512 + tid;
    gload16(ktb + u * 16, &Kb[0][u * 16]);
    gload16(vtb + u * 16, &Vb[0][u * 16]);
  }

  int cur = 0;
  for (int t = 0; t < ntb; ++t) {
    // issue next tile's staging; keep it in flight across the barrier (T4)
    if (t + 1 < ntb) {
      const char* kt2 = ktb + ((size_t)(t + 1) << 14);
      const char* vt2 = vtb + ((size_t)(t + 1) << 14);
      const int nb = cur ^ 1;
#pragma unroll
      for (int i = 0; i < 2; ++i) {
        int u = i * 512 + tid;
        gload16(kt2 + u * 16, &Kb[nb][u * 16]);
        gload16(vt2 + u * 16, &Vb[nb][u * 16]);
      }
      asm volatile("s_waitcnt vmcnt(4)" ::: "memory");   // tile-t loads done; t+1 in flight
    } else {
      asm volatile("s_waitcnt vmcnt(0)" ::: "memory");
    }
    __builtin_amdgcn_s_barrier();
    asm volatile("" ::: "memory");

    // ---- QK^T (swapped): lane holds S[q=q32][k = t*64 + kt2*32 + crow(r,h)] ----
    f32x16 s[2];
#pragma unroll
    for (int kt2 = 0; kt2 < 2; ++kt2) {
      const int kb = t * 64 + kt2 * 32;
      if (kb + 32 <= nc) {
        s[kt2] = (f32x16)(0.f);
      } else {
#pragma unroll
        for (int ri = 0; ri < 16; ++ri)
          s[kt2][ri] = (kb + (ri >> 2) * 8 + 4 * h + (ri & 3) < nc) ? 0.f : -1e9f;
      }
      const int krow = kt2 * 32 + q32;
      const int ksw  = krow & 15;
      __builtin_amdgcn_s_setprio(1);
#pragma unroll
      for (int c = 0; c < 8; ++c) {
        f16x8 kf = *(const f16x8*)(&Kb[cur][krow * 256 + (((2 * c + h) ^ ksw) << 4)]);
        s[kt2] = __builtin_amdgcn_mfma_f32_32x32x16_f16(kf, qf[c], s[kt2], 0, 0, 0);
      }
      __builtin_amdgcn_s_setprio(0);
    }

    // ---- online softmax: tree max ----
    float mx[16];
#pragma unroll
    for (int r = 0; r < 16; ++r) mx[r] = fmaxf(s[0][r], s[1][r]);
#pragma unroll
    for (int r = 0; r < 8; ++r) mx[r] = fmaxf(mx[r], mx[r + 8]);
#pragma unroll
    for (int r = 0; r < 4; ++r) mx[r] = fmaxf(mx[r], mx[r + 4]);
    float pmax = fmaxf(fmaxf(mx[0], mx[1]), fmaxf(mx[2], mx[3]));
    pmax = fmaxf(pmax, __shfl_xor(pmax, 32));

    if (!__all(pmax - mrow <= 8.f)) {          // defer-max (T13)
      float mnew = fmaxf(mrow, pmax);
      float scf = __expf(mrow - mnew);
#pragma unroll
      for (int dvt = 0; dvt < 4; ++dvt)
#pragma unroll
        for (int r = 0; r < 16; ++r) oacc[dvt][r] *= scf;
      lrow *= scf;
      mrow = mnew;
    }

    // exp + tree sum
    float ps[16];
#pragma unroll
    for (int r = 0; r < 16; ++r) {
      s[0][r] = __expf(s[0][r] - mrow);
      s[1][r] = __expf(s[1][r] - mrow);
      ps[r] = s[0][r] + s[1][r];
    }
#pragma unroll
    for (int r = 0; r < 8; ++r) ps[r] += ps[r + 8];
#pragma unroll
    for (int r = 0; r < 4; ++r) ps[r] += ps[r + 4];
    float psum = (ps[0] + ps[1]) + (ps[2] + ps[3]);
    psum += __shfl_xor(psum, 32);
    lrow += psum;

    // ---- pack P to f16 pairs ----
    uint_t pkA[2][4], pkB[2][4];
#pragma unroll
    for (int t2 = 0; t2 < 2; ++t2)
#pragma unroll
      for (int m = 0; m < 4; ++m) {
        pkA[t2][m] = __builtin_bit_cast(uint_t,
            __builtin_amdgcn_cvt_pkrtz(s[t2][4 * m + 0], s[t2][4 * m + 1]));
        pkB[t2][m] = __builtin_bit_cast(uint_t,
            __builtin_amdgcn_cvt_pkrtz(s[t2][4 * m + 2], s[t2][4 * m + 3]));
      }

    // ---- PV (swapped): O^T += V^T * P^T ----
#pragma unroll
    for (int ks = 0; ks < 4; ++ks) {
      const int sk = ks & 1, tt = ks >> 1;
      uint_t Ao = h ? pkA[tt][2 * sk + 1] : pkA[tt][2 * sk];
      uint_t Bo = h ? pkB[tt][2 * sk + 1] : pkB[tt][2 * sk];
      uint_t As = h ? pkA[tt][2 * sk]     : pkA[tt][2 * sk + 1];
      uint_t Bs = h ? pkB[tt][2 * sk]     : pkB[tt][2 * sk + 1];
      uint_t Ax = (uint_t)__shfl_xor((int)As, 32);
      uint_t Bx = (uint_t)__shfl_xor((int)Bs, 32);
      union { uint_t u[4]; f16x8 v; } pa;
      pa.u[0] = h ? Ax : Ao;
      pa.u[1] = h ? Bx : Bo;
      pa.u[2] = h ? Ao : Ax;
      pa.u[3] = h ? Bo : Bx;
      __builtin_amdgcn_s_setprio(1);
#pragma unroll
      for (int dvt = 0; dvt < 4; ++dvt) {
        const int dv = dvt * 32 + q32;
        f16x8 vf = *(const f16x8*)(&Vb[cur][dv * 128 + (((2 * ks + h) ^ (dv & 7)) << 4)]);
        oacc[dvt] = __builtin_amdgcn_mfma_f32_32x32x16_f16(vf, pa.v, oacc[dvt], 0, 0, 0);
      }
      __builtin_amdgcn_s_setprio(0);
    }

    // all reads of buf[cur] done; next iter may overwrite it
    asm volatile("" ::: "memory");
    __builtin_amdgcn_s_barrier();
    asm volatile("" ::: "memory");
    cur ^= 1;
  }

  // ---- epilogue ----
  const float inv = 1.0f / lrow;
  float* op = Og + hbase + (size_t)qrow * DIM;
#pragma unroll
  for (int dvt = 0; dvt < 4; ++dvt)
#pragma unroll
    for (int rq = 0; rq < 4; ++rq) {
      float4 o4;
      o4.x = oacc[dvt][4 * rq + 0] * inv;
      o4.y = oacc[dvt][4 * rq + 1] * inv;
      o4.z = oacc[dvt][4 * rq + 2] * inv;
      o4.w = oacc[dvt][4 * rq + 3] * inv;
      *(float4*)(op + dvt * 32 + rq * 8 + h * 4) = o4;
    }
}

// ---------------- fallback (verified round-1 kernel) for small ws ----------------
#define QT 64
#define P_STRIDE 72
#define VT_STRIDE 76
typedef _Float16 f16x4_t __attribute__((ext_vector_type(4)));
__global__ __launch_bounds__(256, 2)
void attn_fwd_fb(const float* __restrict__ Qg, const float* __restrict__ Kg,
                 const float* __restrict__ Vg, const int* __restrict__ Mg,
                 float* __restrict__ Og) {
  __shared__ __align__(16) ushort_t K_lds[QT * DIM];
  __shared__ __align__(16) ushort_t Vt_lds[DIM * VT_STRIDE];
  __shared__ __align__(16) ushort_t P_lds[QT * P_STRIDE];
  __shared__ int M_lds[KVBLK];
  const int tid  = threadIdx.x;
  const int lane = tid & 63;
  const int w    = tid >> 6;
  const int li   = lane & 15;
  const int g    = lane >> 4;
  const int bid  = blockIdx.x;
  const int nid  = (bid & 7) * 256 + (bid >> 3);
  const int head = nid >> 5;
  const int qblk = nid & 31;
  const size_t hbase = (size_t)head * SEQ * DIM;
  const int bb = head >> 4;
  f16x8 qf[4];
  {
    const float* qp = Qg + hbase + (size_t)(qblk * QT + w * 16 + li) * DIM + g * 8;
#pragma unroll
    for (int d0 = 0; d0 < 4; ++d0) {
      float4 a = *(const float4*)(qp + d0 * 32);
      float4 b = *(const float4*)(qp + d0 * 32 + 4);
      f16x8 f;
      f[0]=(f16)a.x; f[1]=(f16)a.y; f[2]=(f16)a.z; f[3]=(f16)a.w;
      f[4]=(f16)b.x; f[5]=(f16)b.y; f[6]=(f16)b.z; f[7]=(f16)b.w;
      qf[d0] = f;
    }
  }
  float mrow[4], lrow[4];
  f32x4 oacc[8];
#pragma unroll
  for (int r = 0; r < 4; ++r) { mrow[r] = -INFINITY; lrow[r] = 0.f; }
#pragma unroll
  for (int dt = 0; dt < 8; ++dt) oacc[dt] = (f32x4)(0.f);
  for (int t = 0; t < NTMAX; ++t) {
    const int k0 = t * KVBLK;
    __syncthreads();
    {
      const float4* kgp = (const float4*)(Kg + hbase + (size_t)k0 * DIM);
#pragma unroll
      for (int rr = 0; rr < 8; ++rr) {
        int fi = rr * 256 + tid;
        int krow = fi >> 5;
        int d4 = fi & 31;
        float4 v = kgp[fi];
        union { f16 h[4]; uint2 u; } c;
        c.h[0]=(f16)v.x; c.h[1]=(f16)v.y; c.h[2]=(f16)v.z; c.h[3]=(f16)v.w;
        int off = krow * 256 + ((d4 * 8) ^ ((krow & 7) << 4));
        *(uint2*)((char*)K_lds + off) = c.u;
      }
    }
    {
      const float* vgp = Vg + hbase + (size_t)k0 * DIM;
#pragma unroll
      for (int rr = 0; rr < 16; ++rr) {
        int u = rr * 256 + tid;
        int d = u & 127;
        int k2 = (u >> 7) * 2;
        float v0 = vgp[(size_t)k2 * DIM + d];
        float v1 = vgp[(size_t)(k2 + 1) * DIM + d];
        union { f16 h[2]; unsigned int u32; } c;
        c.h[0]=(f16)v0; c.h[1]=(f16)v1;
        *(unsigned int*)(Vt_lds + d * VT_STRIDE + k2) = c.u32;
      }
    }
    if (tid < KVBLK) M_lds[tid] = Mg[(size_t)bb * SEQ + k0 + tid];
    __syncthreads();
    f32x4 sacc[4];
#pragma unroll
    for (int kt = 0; kt < 4; ++kt) sacc[kt] = (f32x4)(0.f);
#pragma unroll
    for (int kt = 0; kt < 4; ++kt) {
      const int krow = kt * 16 + li;
      const int swz = (krow & 7) << 4;
#pragma unroll
      for (int d0 = 0; d0 < 4; ++d0) {
        f16x8 kf = *(const f16x8*)((const char*)K_lds + krow * 256 + ((d0 * 64 + g * 16) ^ swz));
        sacc[kt] = __builtin_amdgcn_mfma_f32_16x16x32_f16(qf[d0], kf, sacc[kt], 0, 0, 0);
      }
    }
    float tmax[4] = {-INFINITY, -INFINITY, -INFINITY, -INFINITY};
#pragma unroll
    for (int kt = 0; kt < 4; ++kt) {
      const bool ok = (M_lds[kt * 16 + li] != 0);
#pragma unroll
      for (int r = 0; r < 4; ++r) {
        float sv = ok ? sacc[kt][r] : -1e9f;
        sacc[kt][r] = sv;
        tmax[r] = fmaxf(tmax[r], sv);
      }
    }
#pragma unroll
    for (int r = 0; r < 4; ++r) {
      tmax[r] = fmaxf(tmax[r], __shfl_xor(tmax[r], 1));
      tmax[r] = fmaxf(tmax[r], __shfl_xor(tmax[r], 2));
      tmax[r] = fmaxf(tmax[r], __shfl_xor(tmax[r], 4));
      tmax[r] = fmaxf(tmax[r], __shfl_xor(tmax[r], 8));
    }
    float sc[4], psum[4];
#pragma unroll
    for (int r = 0; r < 4; ++r) {
      float mnew = fmaxf(mrow[r], tmax[r]);
      sc[r] = __expf(mrow[r] - mnew);
      mrow[r] = mnew;
      psum[r] = 0.f;
    }
#pragma unroll
    for (int dt = 0; dt < 8; ++dt)
#pragma unroll
      for (int r = 0; r < 4; ++r) oacc[dt][r] *= sc[r];
#pragma unroll
    for (int kt = 0; kt < 4; ++kt) {
#pragma unroll
      for (int r = 0; r < 4; ++r) {
        float p = __expf(sacc[kt][r] - mrow[r]);
        psum[r] += p;
        P_lds[(w * 16 + g * 4 + r) * P_STRIDE + kt * 16 + li] =
            __builtin_bit_cast(ushort_t, (f16)p);
      }
    }
#pragma unroll
    for (int r = 0; r < 4; ++r) {
      psum[r] += __shfl_xor(psum[r], 1);
      psum[r] += __shfl_xor(psum[r], 2);
      psum[r] += __shfl_xor(psum[r], 4);
      psum[r] += __shfl_xor(psum[r], 8);
      lrow[r] = lrow[r] * sc[r] + psum[r];
    }
#pragma unroll
    for (int c = 0; c < 2; ++c) {
      f16x8 pa = *(const f16x8*)(P_lds + (w * 16 + li) * P_STRIDE + c * 32 + g * 8);
#pragma unroll
      for (int dt = 0; dt < 8; ++dt) {
        const ushort_t* vp = Vt_lds + (dt * 16 + li) * VT_STRIDE + c * 32 + g * 8;
        f16x4_t v0 = *(const f16x4_t*)vp;
        f16x4_t v1 = *(const f16x4_t*)(vp + 4);
        f16x8 vf;
        vf[0]=v0[0]; vf[1]=v0[1]; vf[2]=v0[2]; vf[3]=v0[3];
        vf[4]=v1[0]; vf[5]=v1[1]; vf[6]=v1[2]; vf[7]=v1[3];
        oacc[dt] = __builtin_amdgcn_mfma_f32_16x16x32_f16(pa, vf, oacc[dt], 0, 0, 0);
      }
    }
  }
#pragma unroll
  for (int r = 0; r < 4; ++r) {
    float inv = 1.0f / lrow[r];
    float* op = Og + hbase + (size_t)(qblk * QT + w * 16 + g * 4 + r) * DIM + li;
#pragma unroll
    for (int dt = 0; dt < 8; ++dt) op[dt * 16] = oacc[dt][r] * inv;
  }
}

extern "C" void kernel_launch(void* const* d_in, const int* in_sizes, int n_in,
                              void* d_out, int out_size, void* d_ws, size_t ws_size,
                              hipStream_t stream) {
  (void)in_sizes; (void)n_in; (void)out_size;
  const float* Q = (const float*)d_in[0];
  const float* K = (const float*)d_in[1];
  const float* V = (const float*)d_in[2];
  const int*   M = (const int*)d_in[3];
  float*       O = (float*)d_out;

  const size_t half = (size_t)2048 * TILE_BYTES;         // 33.5 MB each
  const size_t cidx_off  = 2 * half;
  const size_t ncomp_off = cidx_off + (size_t)4 * SEQ * sizeof(int);
  const size_t need = ncomp_off + 4 * sizeof(int);

  if (ws_size >= need) {
    char* Kws = (char*)d_ws;
    char* Vws = Kws + half;
    int*  cidx  = (int*)((char*)d_ws + cidx_off);
    int*  ncomp = (int*)((char*)d_ws + ncomp_off);
    scan_mask<<<dim3(4), dim3(64), 0, stream>>>(M, cidx, ncomp);
    prep_k<<<dim3(2048), dim3(256), 0, stream>>>(K, Kws, cidx, ncomp);
    prep_v<<<dim3(2048), dim3(256), 0, stream>>>(V, Vws, cidx, ncomp);
    attn_main32<<<dim3(512), dim3(512), 0, stream>>>(Q, Kws, Vws, ncomp, O);
  } else {
    attn_fwd_fb<<<dim3(2048), dim3(256), 0, stream>>>(Q, K, V, M, O);
  }
}

// Round 7
// 142.023 us; speedup vs baseline: 2.7779x; 1.0110x over previous
//
#include <hip/hip_runtime.h>

typedef _Float16 f16;
typedef _Float16 f16x8 __attribute__((ext_vector_type(8)));
typedef _Float16 f16x4 __attribute__((ext_vector_type(4)));
typedef float f32x4 __attribute__((ext_vector_type(4)));
typedef float f32x16 __attribute__((ext_vector_type(16)));
typedef unsigned short ushort_t;
typedef unsigned int uint_t;

#define SEQ 2048
#define DIM 128
#define KVBLK 64
#define NTMAX (SEQ / KVBLK)   // 32 k-tiles max
#define TILE_BYTES 16384      // 64x128 (or 128x64) f16 tile image

typedef __attribute__((address_space(3))) char lds_char;
typedef __attribute__((address_space(1))) const char glb_char;

__device__ __forceinline__ void gload16(const void* g, void* l) {
  __builtin_amdgcn_global_load_lds((glb_char*)g, (lds_char*)l, 16, 0, 0);
}

// ---------------- scan: per-batch compaction of unmasked key indices ----------------
__global__ __launch_bounds__(64)
void scan_mask(const int* __restrict__ Mg, int* __restrict__ cidx, int* __restrict__ ncomp) {
  const int b = blockIdx.x;
  const int l = threadIdx.x;
  int m[32];
  int cnt = 0;
  const int* mp = Mg + (size_t)b * SEQ + l * 32;
#pragma unroll
  for (int j = 0; j < 32; ++j) { m[j] = mp[j]; cnt += (m[j] != 0) ? 1 : 0; }
  int inc = cnt;
  for (int ofs = 1; ofs < 64; ofs <<= 1) {
    int v = __shfl_up(inc, ofs);
    if (l >= ofs) inc += v;
  }
  int pos = inc - cnt;
  int* cp = cidx + (size_t)b * SEQ;
  for (int j = 0; j < 32; ++j)
    if (m[j] != 0) cp[pos++] = l * 32 + j;
  if (l == 63) ncomp[b] = inc;
}

// ---------------- pre-pass: gathered K -> f16, swizzled 64x128 tile images ----------------
// f16 (krow,d) -> byte  krow*256 + (((d>>3) ^ (krow&15))<<4) + (d&7)*2
__global__ __launch_bounds__(256)
void prep_k(const float* __restrict__ Kg, char* __restrict__ Kws,
            const int* __restrict__ cidx, const int* __restrict__ ncomp) {
  const int tid  = threadIdx.x;
  const int blk  = blockIdx.x;        // head*32 + t
  const int head = blk >> 5, t = blk & 31;
  const int b    = head >> 4;
  const int nc   = ncomp[b];
  if (t >= ((nc + 63) >> 6)) return;
  const float* hin = Kg + (size_t)head * SEQ * DIM;
  const int* cp = cidx + (size_t)b * SEQ;
  char* out = Kws + (size_t)blk * TILE_BYTES;
#pragma unroll
  for (int i = 0; i < 4; ++i) {
    int u = i * 256 + tid;
    int krow = u >> 4;
    int un   = u & 15;
    int kidx = t * 64 + krow;
    union { f16 h[8]; uint4 u4; } c;
    if (kidx < nc) {
      const float* p = hin + (size_t)cp[kidx] * DIM + un * 8;
      float4 a = *(const float4*)p;
      float4 bq = *(const float4*)(p + 4);
      c.h[0]=(f16)a.x;  c.h[1]=(f16)a.y;  c.h[2]=(f16)a.z;  c.h[3]=(f16)a.w;
      c.h[4]=(f16)bq.x; c.h[5]=(f16)bq.y; c.h[6]=(f16)bq.z; c.h[7]=(f16)bq.w;
    } else {
      c.u4 = uint4{0, 0, 0, 0};
    }
    *(uint4*)(out + krow * 256 + ((un ^ (krow & 15)) << 4)) = c.u4;
  }
}

// ---------------- pre-pass: gathered V -> f16 transposed, swizzled 128x64 tiles ----------------
// f16 (k,dv) -> byte  dv*128 + (((k>>3) ^ (dv&7))<<4) + (k&7)*2
__global__ __launch_bounds__(256)
void prep_v(const float* __restrict__ Vg, char* __restrict__ Vws,
            const int* __restrict__ cidx, const int* __restrict__ ncomp) {
  __shared__ ushort_t Vs[KVBLK * 133];
  const int tid  = threadIdx.x;
  const int blk  = blockIdx.x;
  const int head = blk >> 5, t = blk & 31;
  const int b    = head >> 4;
  const int nc   = ncomp[b];
  if (t >= ((nc + 63) >> 6)) return;
  const float* hin = Vg + (size_t)head * SEQ * DIM;
  const int* cp = cidx + (size_t)b * SEQ;
  char* out = Vws + (size_t)blk * TILE_BYTES;
#pragma unroll
  for (int i = 0; i < 4; ++i) {
    int u = i * 256 + tid;
    int k  = u >> 4;
    int d0 = (u & 15) * 8;
    int kidx = t * 64 + k;
    f16 h[8];
    if (kidx < nc) {
      const float* p = hin + (size_t)cp[kidx] * DIM + d0;
      float4 a = *(const float4*)p;
      float4 bq = *(const float4*)(p + 4);
      h[0]=(f16)a.x;  h[1]=(f16)a.y;  h[2]=(f16)a.z;  h[3]=(f16)a.w;
      h[4]=(f16)bq.x; h[5]=(f16)bq.y; h[6]=(f16)bq.z; h[7]=(f16)bq.w;
    } else {
#pragma unroll
      for (int j = 0; j < 8; ++j) h[j] = (f16)0.f;
    }
#pragma unroll
    for (int j = 0; j < 8; ++j)
      Vs[k * 133 + d0 + j] = __builtin_bit_cast(ushort_t, h[j]);
  }
  __syncthreads();
#pragma unroll
  for (int i = 0; i < 4; ++i) {
    int u = i * 256 + tid;
    int d  = u >> 3;
    int un = u & 7;
    union { f16 h[8]; uint4 u4; } c;
#pragma unroll
    for (int j = 0; j < 8; ++j)
      c.h[j] = __builtin_bit_cast(f16, Vs[(un * 8 + j) * 133 + d]);
    *(uint4*)(out + d * 128 + ((un ^ (d & 7)) << 4)) = c.u4;
  }
}

// ---- PV accumulate: O^T += V^T * P^T  (pk from PREVIOUS tile) ----
__device__ __forceinline__ void pv_accum(const char* __restrict__ Vbuf,
                                         const uint_t pkA[2][4], const uint_t pkB[2][4],
                                         f32x16 oacc[4], int q32, int h) {
#pragma unroll
  for (int ks = 0; ks < 4; ++ks) {
    const int sk = ks & 1, tt = ks >> 1;
    uint_t Ao = h ? pkA[tt][2 * sk + 1] : pkA[tt][2 * sk];
    uint_t Bo = h ? pkB[tt][2 * sk + 1] : pkB[tt][2 * sk];
    uint_t As = h ? pkA[tt][2 * sk]     : pkA[tt][2 * sk + 1];
    uint_t Bs = h ? pkB[tt][2 * sk]     : pkB[tt][2 * sk + 1];
    uint_t Ax = (uint_t)__shfl_xor((int)As, 32);
    uint_t Bx = (uint_t)__shfl_xor((int)Bs, 32);
    union { uint_t u[4]; f16x8 v; } pa;
    pa.u[0] = h ? Ax : Ao;
    pa.u[1] = h ? Bx : Bo;
    pa.u[2] = h ? Ao : Ax;
    pa.u[3] = h ? Bo : Bx;
    __builtin_amdgcn_s_setprio(1);
#pragma unroll
    for (int dvt = 0; dvt < 4; ++dvt) {
      const int dv = dvt * 32 + q32;
      f16x8 vf = *(const f16x8*)(&Vbuf[dv * 128 + (((2 * ks + h) ^ (dv & 7)) << 4)]);
      oacc[dvt] = __builtin_amdgcn_mfma_f32_32x32x16_f16(vf, pa.v, oacc[dvt], 0, 0, 0);
    }
    __builtin_amdgcn_s_setprio(0);
  }
}

// ---------------- main: 8 waves x QBLK32, PV deferred one tile (T15-lite) ----------------
__global__ __launch_bounds__(512, 2)
void attn_main32(const float* __restrict__ Qg, const char* __restrict__ Kws,
                 const char* __restrict__ Vws, const int* __restrict__ ncomp,
                 float* __restrict__ Og) {
  __shared__ __align__(16) char Kb[2][TILE_BYTES];
  __shared__ __align__(16) char Vb[2][TILE_BYTES];

  const int tid  = threadIdx.x;
  const int lane = tid & 63;
  const int q32  = lane & 31;
  const int h    = lane >> 5;

  const int bid  = blockIdx.x;                  // 0..511
  const int head = (bid & 7) * 8 + (bid >> 6);  // XCD grouping
  const int qblk = (bid >> 3) & 7;
  const size_t hbase = (size_t)head * SEQ * DIM;
  const int bb = head >> 4;

  const int nc  = ncomp[bb];
  const int ntb = (nc + 63) >> 6;

  const char* ktb = Kws + ((size_t)(head * NTMAX) << 14);
  const char* vtb = Vws + ((size_t)(head * NTMAX) << 14);

  const int qrow = qblk * 256 + (tid >> 6) * 32 + q32;

  // Q fragments: lane holds Q[qrow][d = 16c + 8h + j]
  f16x8 qf[8];
  {
    const float* qp = Qg + hbase + (size_t)qrow * DIM + h * 8;
#pragma unroll
    for (int c = 0; c < 8; ++c) {
      float4 a = *(const float4*)(qp + c * 16);
      float4 b = *(const float4*)(qp + c * 16 + 4);
      f16x8 f;
      f[0]=(f16)a.x; f[1]=(f16)a.y; f[2]=(f16)a.z; f[3]=(f16)a.w;
      f[4]=(f16)b.x; f[5]=(f16)b.y; f[6]=(f16)b.z; f[7]=(f16)b.w;
      qf[c] = f;
    }
  }

  f32x16 oacc[4];
#pragma unroll
  for (int dvt = 0; dvt < 4; ++dvt) oacc[dvt] = (f32x16)(0.f);
  float mrow = -INFINITY, lrow = 0.f;

  // packed P of the previous tile (consumed by pv_accum one iter later)
  uint_t pkPA[2][4], pkPB[2][4];
#pragma unroll
  for (int t2 = 0; t2 < 2; ++t2)
#pragma unroll
    for (int m = 0; m < 4; ++m) { pkPA[t2][m] = 0; pkPB[t2][m] = 0; }

  // prologue: stage K(0) only (V(0) staged at iter 0)
#pragma unroll
  for (int i = 0; i < 2; ++i) {
    int u = i * 512 + tid;
    gload16(ktb + u * 16, &Kb[0][u * 16]);
  }

  int cur = 0;
  for (int t = 0; t < ntb; ++t) {
    // ---- stage K(t+1) [wrap: harmless] into Kb[cur^1], V(t) into Vb[cur] ----
    {
      const int tn = (t + 1 == ntb) ? 0 : t + 1;
      const char* kt2 = ktb + ((size_t)tn << 14);
      const char* vt2 = vtb + ((size_t)t << 14);
      const int nb = cur ^ 1;
#pragma unroll
      for (int i = 0; i < 2; ++i) {
        int u = i * 512 + tid;
        gload16(kt2 + u * 16, &Kb[nb][u * 16]);
      }
#pragma unroll
      for (int i = 0; i < 2; ++i) {
        int u = i * 512 + tid;
        gload16(vt2 + u * 16, &Vb[cur][u * 16]);
      }
    }
    // K(t) and V(t-1) were the 4 loads issued last iter; keep this iter's 4 in flight
    asm volatile("s_waitcnt vmcnt(4)" ::: "memory");
    __builtin_amdgcn_s_barrier();
    asm volatile("" ::: "memory");

    // ---- QK^T(t) (swapped): lane holds S[q=q32][k = t*64 + kt2*32 + crow(r,h)] ----
    f32x16 s0, s1;
    {
      const int kb0 = t * 64;
      if (kb0 + 32 <= nc) {
        s0 = (f32x16)(0.f);
      } else {
#pragma unroll
        for (int ri = 0; ri < 16; ++ri)
          s0[ri] = (kb0 + (ri >> 2) * 8 + 4 * h + (ri & 3) < nc) ? 0.f : -1e9f;
      }
      const int kb1 = t * 64 + 32;
      if (kb1 + 32 <= nc) {
        s1 = (f32x16)(0.f);
      } else {
#pragma unroll
        for (int ri = 0; ri < 16; ++ri)
          s1[ri] = (kb1 + (ri >> 2) * 8 + 4 * h + (ri & 3) < nc) ? 0.f : -1e9f;
      }
      __builtin_amdgcn_s_setprio(1);
      {
        const int krow = q32;
        const int ksw  = krow & 15;
#pragma unroll
        for (int c = 0; c < 8; ++c) {
          f16x8 kf = *(const f16x8*)(&Kb[cur][krow * 256 + (((2 * c + h) ^ ksw) << 4)]);
          s0 = __builtin_amdgcn_mfma_f32_32x32x16_f16(kf, qf[c], s0, 0, 0, 0);
        }
      }
      {
        const int krow = 32 + q32;
        const int ksw  = krow & 15;
#pragma unroll
        for (int c = 0; c < 8; ++c) {
          f16x8 kf = *(const f16x8*)(&Kb[cur][krow * 256 + (((2 * c + h) ^ ksw) << 4)]);
          s1 = __builtin_amdgcn_mfma_f32_32x32x16_f16(kf, qf[c], s1, 0, 0, 0);
        }
      }
      __builtin_amdgcn_s_setprio(0);
    }

    // ---- PV(t-1): independent of QK(t) and SM(t) — overlaps both ----
    if (t > 0) {
      pv_accum(&Vb[cur ^ 1][0], pkPA, pkPB, oacc, q32, h);
    }

    // ---- SM(t): max tree, defer-max rescale, exp, psum, pack -> pkP ----
    {
      float mx[16];
#pragma unroll
      for (int r = 0; r < 16; ++r) mx[r] = fmaxf(s0[r], s1[r]);
#pragma unroll
      for (int r = 0; r < 8; ++r) mx[r] = fmaxf(mx[r], mx[r + 8]);
#pragma unroll
      for (int r = 0; r < 4; ++r) mx[r] = fmaxf(mx[r], mx[r + 4]);
      float pmax = fmaxf(fmaxf(mx[0], mx[1]), fmaxf(mx[2], mx[3]));
      pmax = fmaxf(pmax, __shfl_xor(pmax, 32));

      if (!__all(pmax - mrow <= 8.f)) {          // defer-max (T13)
        float mnew = fmaxf(mrow, pmax);
        float scf = __expf(mrow - mnew);
#pragma unroll
        for (int dvt = 0; dvt < 4; ++dvt)
#pragma unroll
          for (int r = 0; r < 16; ++r) oacc[dvt][r] *= scf;
        lrow *= scf;
        mrow = mnew;
      }

      float ps[16];
#pragma unroll
      for (int r = 0; r < 16; ++r) {
        s0[r] = __expf(s0[r] - mrow);
        s1[r] = __expf(s1[r] - mrow);
        ps[r] = s0[r] + s1[r];
      }
#pragma unroll
      for (int r = 0; r < 8; ++r) ps[r] += ps[r + 8];
#pragma unroll
      for (int r = 0; r < 4; ++r) ps[r] += ps[r + 4];
      float psum = (ps[0] + ps[1]) + (ps[2] + ps[3]);
      psum += __shfl_xor(psum, 32);
      lrow += psum;

#pragma unroll
      for (int m = 0; m < 4; ++m) {
        pkPA[0][m] = __builtin_bit_cast(uint_t,
            __builtin_amdgcn_cvt_pkrtz(s0[4 * m + 0], s0[4 * m + 1]));
        pkPB[0][m] = __builtin_bit_cast(uint_t,
            __builtin_amdgcn_cvt_pkrtz(s0[4 * m + 2], s0[4 * m + 3]));
        pkPA[1][m] = __builtin_bit_cast(uint_t,
            __builtin_amdgcn_cvt_pkrtz(s1[4 * m + 0], s1[4 * m + 1]));
        pkPB[1][m] = __builtin_bit_cast(uint_t,
            __builtin_amdgcn_cvt_pkrtz(s1[4 * m + 2], s1[4 * m + 3]));
      }
    }

    asm volatile("" ::: "memory");
    __builtin_amdgcn_s_barrier();
    asm volatile("" ::: "memory");
    cur ^= 1;
  }

  // ---- epilogue: drain V(ntb-1), final PV, normalize, store ----
  asm volatile("s_waitcnt vmcnt(0)" ::: "memory");
  __builtin_amdgcn_s_barrier();
  asm volatile("" ::: "memory");
  if (ntb > 0) {
    pv_accum(&Vb[cur ^ 1][0], pkPA, pkPB, oacc, q32, h);
  }

  const float inv = 1.0f / lrow;
  float* op = Og + hbase + (size_t)qrow * DIM;
#pragma unroll
  for (int dvt = 0; dvt < 4; ++dvt)
#pragma unroll
    for (int rq = 0; rq < 4; ++rq) {
      float4 o4;
      o4.x = oacc[dvt][4 * rq + 0] * inv;
      o4.y = oacc[dvt][4 * rq + 1] * inv;
      o4.z = oacc[dvt][4 * rq + 2] * inv;
      o4.w = oacc[dvt][4 * rq + 3] * inv;
      *(float4*)(op + dvt * 32 + rq * 8 + h * 4) = o4;
    }
}

// ---------------- fallback (verified round-1 kernel) for small ws ----------------
#define QT 64
#define P_STRIDE 72
#define VT_STRIDE 76
typedef _Float16 f16x4_t __attribute__((ext_vector_type(4)));
__global__ __launch_bounds__(256, 2)
void attn_fwd_fb(const float* __restrict__ Qg, const float* __restrict__ Kg,
                 const float* __restrict__ Vg, const int* __restrict__ Mg,
                 float* __restrict__ Og) {
  __shared__ __align__(16) ushort_t K_lds[QT * DIM];
  __shared__ __align__(16) ushort_t Vt_lds[DIM * VT_STRIDE];
  __shared__ __align__(16) ushort_t P_lds[QT * P_STRIDE];
  __shared__ int M_lds[KVBLK];
  const int tid  = threadIdx.x;
  const int lane = tid & 63;
  const int w    = tid >> 6;
  const int li   = lane & 15;
  const int g    = lane >> 4;
  const int bid  = blockIdx.x;
  const int nid  = (bid & 7) * 256 + (bid >> 3);
  const int head = nid >> 5;
  const int qblk = nid & 31;
  const size_t hbase = (size_t)head * SEQ * DIM;
  const int bb = head >> 4;
  f16x8 qf[4];
  {
    const float* qp = Qg + hbase + (size_t)(qblk * QT + w * 16 + li) * DIM + g * 8;
#pragma unroll
    for (int d0 = 0; d0 < 4; ++d0) {
      float4 a = *(const float4*)(qp + d0 * 32);
      float4 b = *(const float4*)(qp + d0 * 32 + 4);
      f16x8 f;
      f[0]=(f16)a.x; f[1]=(f16)a.y; f[2]=(f16)a.z; f[3]=(f16)a.w;
      f[4]=(f16)b.x; f[5]=(f16)b.y; f[6]=(f16)b.z; f[7]=(f16)b.w;
      qf[d0] = f;
    }
  }
  float mrow[4], lrow[4];
  f32x4 oacc[8];
#pragma unroll
  for (int r = 0; r < 4; ++r) { mrow[r] = -INFINITY; lrow[r] = 0.f; }
#pragma unroll
  for (int dt = 0; dt < 8; ++dt) oacc[dt] = (f32x4)(0.f);
  for (int t = 0; t < NTMAX; ++t) {
    const int k0 = t * KVBLK;
    __syncthreads();
    {
      const float4* kgp = (const float4*)(Kg + hbase + (size_t)k0 * DIM);
#pragma unroll
      for (int rr = 0; rr < 8; ++rr) {
        int fi = rr * 256 + tid;
        int krow = fi >> 5;
        int d4 = fi & 31;
        float4 v = kgp[fi];
        union { f16 h[4]; uint2 u; } c;
        c.h[0]=(f16)v.x; c.h[1]=(f16)v.y; c.h[2]=(f16)v.z; c.h[3]=(f16)v.w;
        int off = krow * 256 + ((d4 * 8) ^ ((krow & 7) << 4));
        *(uint2*)((char*)K_lds + off) = c.u;
      }
    }
    {
      const float* vgp = Vg + hbase + (size_t)k0 * DIM;
#pragma unroll
      for (int rr = 0; rr < 16; ++rr) {
        int u = rr * 256 + tid;
        int d = u & 127;
        int k2 = (u >> 7) * 2;
        float v0 = vgp[(size_t)k2 * DIM + d];
        float v1 = vgp[(size_t)(k2 + 1) * DIM + d];
        union { f16 h[2]; unsigned int u32; } c;
        c.h[0]=(f16)v0; c.h[1]=(f16)v1;
        *(unsigned int*)(Vt_lds + d * VT_STRIDE + k2) = c.u32;
      }
    }
    if (tid < KVBLK) M_lds[tid] = Mg[(size_t)bb * SEQ + k0 + tid];
    __syncthreads();
    f32x4 sacc[4];
#pragma unroll
    for (int kt = 0; kt < 4; ++kt) sacc[kt] = (f32x4)(0.f);
#pragma unroll
    for (int kt = 0; kt < 4; ++kt) {
      const int krow = kt * 16 + li;
      const int swz = (krow & 7) << 4;
#pragma unroll
      for (int d0 = 0; d0 < 4; ++d0) {
        f16x8 kf = *(const f16x8*)((const char*)K_lds + krow * 256 + ((d0 * 64 + g * 16) ^ swz));
        sacc[kt] = __builtin_amdgcn_mfma_f32_16x16x32_f16(qf[d0], kf, sacc[kt], 0, 0, 0);
      }
    }
    float tmax[4] = {-INFINITY, -INFINITY, -INFINITY, -INFINITY};
#pragma unroll
    for (int kt = 0; kt < 4; ++kt) {
      const bool ok = (M_lds[kt * 16 + li] != 0);
#pragma unroll
      for (int r = 0; r < 4; ++r) {
        float sv = ok ? sacc[kt][r] : -1e9f;
        sacc[kt][r] = sv;
        tmax[r] = fmaxf(tmax[r], sv);
      }
    }
#pragma unroll
    for (int r = 0; r < 4; ++r) {
      tmax[r] = fmaxf(tmax[r], __shfl_xor(tmax[r], 1));
      tmax[r] = fmaxf(tmax[r], __shfl_xor(tmax[r], 2));
      tmax[r] = fmaxf(tmax[r], __shfl_xor(tmax[r], 4));
      tmax[r] = fmaxf(tmax[r], __shfl_xor(tmax[r], 8));
    }
    float sc[4], psum[4];
#pragma unroll
    for (int r = 0; r < 4; ++r) {
      float mnew = fmaxf(mrow[r], tmax[r]);
      sc[r] = __expf(mrow[r] - mnew);
      mrow[r] = mnew;
      psum[r] = 0.f;
    }
#pragma unroll
    for (int dt = 0; dt < 8; ++dt)
#pragma unroll
      for (int r = 0; r < 4; ++r) oacc[dt][r] *= sc[r];
#pragma unroll
    for (int kt = 0; kt < 4; ++kt) {
#pragma unroll
      for (int r = 0; r < 4; ++r) {
        float p = __expf(sacc[kt][r] - mrow[r]);
        psum[r] += p;
        P_lds[(w * 16 + g * 4 + r) * P_STRIDE + kt * 16 + li] =
            __builtin_bit_cast(ushort_t, (f16)p);
      }
    }
#pragma unroll
    for (int r = 0; r < 4; ++r) {
      psum[r] += __shfl_xor(psum[r], 1);
      psum[r] += __shfl_xor(psum[r], 2);
      psum[r] += __shfl_xor(psum[r], 4);
      psum[r] += __shfl_xor(psum[r], 8);
      lrow[r] = lrow[r] * sc[r] + psum[r];
    }
#pragma unroll
    for (int c = 0; c < 2; ++c) {
      f16x8 pa = *(const f16x8*)(P_lds + (w * 16 + li) * P_STRIDE + c * 32 + g * 8);
#pragma unroll
      for (int dt = 0; dt < 8; ++dt) {
        const ushort_t* vp = Vt_lds + (dt * 16 + li) * VT_STRIDE + c * 32 + g * 8;
        f16x4_t v0 = *(const f16x4_t*)vp;
        f16x4_t v1 = *(const f16x4_t*)(vp + 4);
        f16x8 vf;
        vf[0]=v0[0]; vf[1]=v0[1]; vf[2]=v0[2]; vf[3]=v0[3];
        vf[4]=v1[0]; vf[5]=v1[1]; vf[6]=v1[2]; vf[7]=v1[3];
        oacc[dt] = __builtin_amdgcn_mfma_f32_16x16x32_f16(pa, vf, oacc[dt], 0, 0, 0);
      }
    }
  }
#pragma unroll
  for (int r = 0; r < 4; ++r) {
    float inv = 1.0f / lrow[r];
    float* op = Og + hbase + (size_t)(qblk * QT + w * 16 + g * 4 + r) * DIM + li;
#pragma unroll
    for (int dt = 0; dt < 8; ++dt) op[dt * 16] = oacc[dt][r] * inv;
  }
}

extern "C" void kernel_launch(void* const* d_in, const int* in_sizes, int n_in,
                              void* d_out, int out_size, void* d_ws, size_t ws_size,
                              hipStream_t stream) {
  (void)in_sizes; (void)n_in; (void)out_size;
  const float* Q = (const float*)d_in[0];
  const float* K = (const float*)d_in[1];
  const float* V = (const float*)d_in[2];
  const int*   M = (const int*)d_in[3];
  float*       O = (float*)d_out;

  const size_t half = (size_t)2048 * TILE_BYTES;         // 33.5 MB each
  const size_t cidx_off  = 2 * half;
  const size_t ncomp_off = cidx_off + (size_t)4 * SEQ * sizeof(int);
  const size_t need = ncomp_off + 4 * sizeof(int);

  if (ws_size >= need) {
    char* Kws = (char*)d_ws;
    char* Vws = Kws + half;
    int*  cidx  = (int*)((char*)d_ws + cidx_off);
    int*  ncomp = (int*)((char*)d_ws + ncomp_off);
    scan_mask<<<dim3(4), dim3(64), 0, stream>>>(M, cidx, ncomp);
    prep_k<<<dim3(2048), dim3(256), 0, stream>>>(K, Kws, cidx, ncomp);
    prep_v<<<dim3(2048), dim3(256), 0, stream>>>(V, Vws, cidx, ncomp);
    attn_main32<<<dim3(512), dim3(512), 0, stream>>>(Q, Kws, Vws, ncomp, O);
  } else {
    attn_fwd_fb<<<dim3(2048), dim3(256), 0, stream>>>(Q, K, V, M, O);
  }
}

// Round 8
// 138.540 us; speedup vs baseline: 2.8477x; 1.0251x over previous
//
#include <hip/hip_runtime.h>

typedef _Float16 f16;
typedef _Float16 f16x8 __attribute__((ext_vector_type(8)));
typedef _Float16 f16x4 __attribute__((ext_vector_type(4)));
typedef float f32x4 __attribute__((ext_vector_type(4)));
typedef float f32x16 __attribute__((ext_vector_type(16)));
typedef unsigned short ushort_t;
typedef unsigned int uint_t;

#define SEQ 2048
#define DIM 128
#define KVBLK 64
#define NTMAX (SEQ / KVBLK)   // 32 k-tiles max
#define TILE_BYTES 16384      // 64x128 (or 128x64) f16 tile image

typedef __attribute__((address_space(3))) char lds_char;
typedef __attribute__((address_space(1))) const char glb_char;

__device__ __forceinline__ void gload16(const void* g, void* l) {
  __builtin_amdgcn_global_load_lds((glb_char*)g, (lds_char*)l, 16, 0, 0);
}

// ---------------- scan: per-batch compaction of unmasked key indices ----------------
__global__ __launch_bounds__(64)
void scan_mask(const int* __restrict__ Mg, int* __restrict__ cidx, int* __restrict__ ncomp) {
  const int b = blockIdx.x;
  const int l = threadIdx.x;
  int m[32];
  int cnt = 0;
  const int* mp = Mg + (size_t)b * SEQ + l * 32;
#pragma unroll
  for (int j = 0; j < 32; ++j) { m[j] = mp[j]; cnt += (m[j] != 0) ? 1 : 0; }
  int inc = cnt;
  for (int ofs = 1; ofs < 64; ofs <<= 1) {
    int v = __shfl_up(inc, ofs);
    if (l >= ofs) inc += v;
  }
  int pos = inc - cnt;
  int* cp = cidx + (size_t)b * SEQ;
  for (int j = 0; j < 32; ++j)
    if (m[j] != 0) cp[pos++] = l * 32 + j;
  if (l == 63) ncomp[b] = inc;
}

// ---------------- pre-pass: gathered K -> f16, swizzled 64x128 tile images ----------------
// f16 (krow,d) -> byte  krow*256 + (((d>>3) ^ (krow&15))<<4) + (d&7)*2
__global__ __launch_bounds__(256)
void prep_k(const float* __restrict__ Kg, char* __restrict__ Kws,
            const int* __restrict__ cidx, const int* __restrict__ ncomp) {
  const int tid  = threadIdx.x;
  const int blk  = blockIdx.x;        // head*32 + t
  const int head = blk >> 5, t = blk & 31;
  const int b    = head >> 4;
  const int nc   = ncomp[b];
  if (t >= ((nc + 63) >> 6)) return;
  const float* hin = Kg + (size_t)head * SEQ * DIM;
  const int* cp = cidx + (size_t)b * SEQ;
  char* out = Kws + (size_t)blk * TILE_BYTES;
#pragma unroll
  for (int i = 0; i < 4; ++i) {
    int u = i * 256 + tid;
    int krow = u >> 4;
    int un   = u & 15;
    int kidx = t * 64 + krow;
    union { f16 h[8]; uint4 u4; } c;
    if (kidx < nc) {
      const float* p = hin + (size_t)cp[kidx] * DIM + un * 8;
      float4 a = *(const float4*)p;
      float4 bq = *(const float4*)(p + 4);
      c.h[0]=(f16)a.x;  c.h[1]=(f16)a.y;  c.h[2]=(f16)a.z;  c.h[3]=(f16)a.w;
      c.h[4]=(f16)bq.x; c.h[5]=(f16)bq.y; c.h[6]=(f16)bq.z; c.h[7]=(f16)bq.w;
    } else {
      c.u4 = uint4{0, 0, 0, 0};
    }
    *(uint4*)(out + krow * 256 + ((un ^ (krow & 15)) << 4)) = c.u4;
  }
}

// ---------------- pre-pass: gathered V -> f16 transposed, swizzled 128x64 tiles ----------------
// f16 (k,dv) -> byte  dv*128 + (((k>>3) ^ (dv&7))<<4) + (k&7)*2
__global__ __launch_bounds__(256)
void prep_v(const float* __restrict__ Vg, char* __restrict__ Vws,
            const int* __restrict__ cidx, const int* __restrict__ ncomp) {
  __shared__ ushort_t Vs[KVBLK * 133];
  const int tid  = threadIdx.x;
  const int blk  = blockIdx.x;
  const int head = blk >> 5, t = blk & 31;
  const int b    = head >> 4;
  const int nc   = ncomp[b];
  if (t >= ((nc + 63) >> 6)) return;
  const float* hin = Vg + (size_t)head * SEQ * DIM;
  const int* cp = cidx + (size_t)b * SEQ;
  char* out = Vws + (size_t)blk * TILE_BYTES;
#pragma unroll
  for (int i = 0; i < 4; ++i) {
    int u = i * 256 + tid;
    int k  = u >> 4;
    int d0 = (u & 15) * 8;
    int kidx = t * 64 + k;
    f16 h[8];
    if (kidx < nc) {
      const float* p = hin + (size_t)cp[kidx] * DIM + d0;
      float4 a = *(const float4*)p;
      float4 bq = *(const float4*)(p + 4);
      h[0]=(f16)a.x;  h[1]=(f16)a.y;  h[2]=(f16)a.z;  h[3]=(f16)a.w;
      h[4]=(f16)bq.x; h[5]=(f16)bq.y; h[6]=(f16)bq.z; h[7]=(f16)bq.w;
    } else {
#pragma unroll
      for (int j = 0; j < 8; ++j) h[j] = (f16)0.f;
    }
#pragma unroll
    for (int j = 0; j < 8; ++j)
      Vs[k * 133 + d0 + j] = __builtin_bit_cast(ushort_t, h[j]);
  }
  __syncthreads();
#pragma unroll
  for (int i = 0; i < 4; ++i) {
    int u = i * 256 + tid;
    int d  = u >> 3;
    int un = u & 7;
    union { f16 h[8]; uint4 u4; } c;
#pragma unroll
    for (int j = 0; j < 8; ++j)
      c.h[j] = __builtin_bit_cast(f16, Vs[(un * 8 + j) * 133 + d]);
    *(uint4*)(out + d * 128 + ((un ^ (d & 7)) << 4)) = c.u4;
  }
}

// ---- build PV A-fragments from packed P (prev tile): pa[ks][j] = P[q32][16ks+8h+j] ----
__device__ __forceinline__ void build_paf(const uint_t pkA[2][4], const uint_t pkB[2][4],
                                          f16x8 paf[4], int h) {
#pragma unroll
  for (int ks = 0; ks < 4; ++ks) {
    const int sk = ks & 1, tt = ks >> 1;
    uint_t Ao = h ? pkA[tt][2 * sk + 1] : pkA[tt][2 * sk];
    uint_t Bo = h ? pkB[tt][2 * sk + 1] : pkB[tt][2 * sk];
    uint_t As = h ? pkA[tt][2 * sk]     : pkA[tt][2 * sk + 1];
    uint_t Bs = h ? pkB[tt][2 * sk]     : pkB[tt][2 * sk + 1];
    uint_t Ax = (uint_t)__shfl_xor((int)As, 32);
    uint_t Bx = (uint_t)__shfl_xor((int)Bs, 32);
    union { uint_t u[4]; f16x8 v; } pa;
    pa.u[0] = h ? Ax : Ao;
    pa.u[1] = h ? Bx : Bo;
    pa.u[2] = h ? Ao : Ax;
    pa.u[3] = h ? Bo : Bx;
    paf[ks] = pa.v;
  }
}

// ---- PV MFMA block: 4 independent oacc chains, no internal fences ----
__device__ __forceinline__ void pv_mfma(const char* __restrict__ Vbuf,
                                        const f16x8 paf[4], f32x16 oacc[4],
                                        int q32, int h) {
  __builtin_amdgcn_s_setprio(1);
#pragma unroll
  for (int ks = 0; ks < 4; ++ks) {
#pragma unroll
    for (int dvt = 0; dvt < 4; ++dvt) {
      const int dv = dvt * 32 + q32;
      f16x8 vf = *(const f16x8*)(&Vbuf[dv * 128 + (((2 * ks + h) ^ (dv & 7)) << 4)]);
      oacc[dvt] = __builtin_amdgcn_mfma_f32_32x32x16_f16(vf, paf[ks], oacc[dvt], 0, 0, 0);
    }
  }
  __builtin_amdgcn_s_setprio(0);
}

// ---------------- main: 8 waves x QBLK32, fence-free interleaved chains ----------------
__global__ __launch_bounds__(512, 2)
void attn_main32(const float* __restrict__ Qg, const char* __restrict__ Kws,
                 const char* __restrict__ Vws, const int* __restrict__ ncomp,
                 float* __restrict__ Og) {
  __shared__ __align__(16) char Kb[2][TILE_BYTES];
  __shared__ __align__(16) char Vb[2][TILE_BYTES];

  const int tid  = threadIdx.x;
  const int lane = tid & 63;
  const int q32  = lane & 31;
  const int h    = lane >> 5;

  const int bid  = blockIdx.x;                  // 0..511
  const int head = (bid & 7) * 8 + (bid >> 6);  // XCD grouping
  const int qblk = (bid >> 3) & 7;
  const size_t hbase = (size_t)head * SEQ * DIM;
  const int bb = head >> 4;

  const int nc  = ncomp[bb];
  const int ntb = (nc + 63) >> 6;

  const char* ktb = Kws + ((size_t)(head * NTMAX) << 14);
  const char* vtb = Vws + ((size_t)(head * NTMAX) << 14);

  const int qrow = qblk * 256 + (tid >> 6) * 32 + q32;

  // Q fragments: lane holds Q[qrow][d = 16c + 8h + j]
  f16x8 qf[8];
  {
    const float* qp = Qg + hbase + (size_t)qrow * DIM + h * 8;
#pragma unroll
    for (int c = 0; c < 8; ++c) {
      float4 a = *(const float4*)(qp + c * 16);
      float4 b = *(const float4*)(qp + c * 16 + 4);
      f16x8 f;
      f[0]=(f16)a.x; f[1]=(f16)a.y; f[2]=(f16)a.z; f[3]=(f16)a.w;
      f[4]=(f16)b.x; f[5]=(f16)b.y; f[6]=(f16)b.z; f[7]=(f16)b.w;
      qf[c] = f;
    }
  }

  f32x16 oacc[4];
#pragma unroll
  for (int dvt = 0; dvt < 4; ++dvt) oacc[dvt] = (f32x16)(0.f);
  float mrow = -INFINITY, lrow = 0.f;

  // packed P of the previous tile
  uint_t pkPA[2][4], pkPB[2][4];
#pragma unroll
  for (int t2 = 0; t2 < 2; ++t2)
#pragma unroll
    for (int m = 0; m < 4; ++m) { pkPA[t2][m] = 0; pkPB[t2][m] = 0; }

  // prologue: stage K(0)
#pragma unroll
  for (int i = 0; i < 2; ++i) {
    int u = i * 512 + tid;
    gload16(ktb + u * 16, &Kb[0][u * 16]);
  }

  int cur = 0;
  for (int t = 0; t < ntb; ++t) {
    // ---- stage K(t+1) into Kb[cur^1], V(t) into Vb[cur] ----
    {
      const int tn = (t + 1 == ntb) ? 0 : t + 1;
      const char* kt2 = ktb + ((size_t)tn << 14);
      const char* vt2 = vtb + ((size_t)t << 14);
      const int nb = cur ^ 1;
#pragma unroll
      for (int i = 0; i < 2; ++i) {
        int u = i * 512 + tid;
        gload16(kt2 + u * 16, &Kb[nb][u * 16]);
      }
#pragma unroll
      for (int i = 0; i < 2; ++i) {
        int u = i * 512 + tid;
        gload16(vt2 + u * 16, &Vb[cur][u * 16]);
      }
    }
    // K(t) and V(t-1) were the 4 loads issued last iter; keep this iter's 4 in flight
    asm volatile("s_waitcnt vmcnt(4)" ::: "memory");
    __builtin_amdgcn_s_barrier();
    asm volatile("" ::: "memory");

    // ---- QK^T(t): two interleaved accumulator chains, one setprio pair ----
    f32x16 s0, s1;
    {
      const int kb0 = t * 64;
      if (kb0 + 32 <= nc) {
        s0 = (f32x16)(0.f);
      } else {
#pragma unroll
        for (int ri = 0; ri < 16; ++ri)
          s0[ri] = (kb0 + (ri >> 2) * 8 + 4 * h + (ri & 3) < nc) ? 0.f : -1e9f;
      }
      const int kb1 = t * 64 + 32;
      if (kb1 + 32 <= nc) {
        s1 = (f32x16)(0.f);
      } else {
#pragma unroll
        for (int ri = 0; ri < 16; ++ri)
          s1[ri] = (kb1 + (ri >> 2) * 8 + 4 * h + (ri & 3) < nc) ? 0.f : -1e9f;
      }
      const int kr0 = q32,      sw0 = kr0 & 15;
      const int kr1 = 32 + q32, sw1 = kr1 & 15;
      __builtin_amdgcn_s_setprio(1);
#pragma unroll
      for (int c = 0; c < 8; ++c) {
        f16x8 k0 = *(const f16x8*)(&Kb[cur][kr0 * 256 + (((2 * c + h) ^ sw0) << 4)]);
        s0 = __builtin_amdgcn_mfma_f32_32x32x16_f16(k0, qf[c], s0, 0, 0, 0);
        f16x8 k1 = *(const f16x8*)(&Kb[cur][kr1 * 256 + (((2 * c + h) ^ sw1) << 4)]);
        s1 = __builtin_amdgcn_mfma_f32_32x32x16_f16(k1, qf[c], s1, 0, 0, 0);
      }
      __builtin_amdgcn_s_setprio(0);
    }

    // ---- PV(t-1): fence-free, independent of QK(t)/SM(t) — scheduler may interleave ----
    if (t > 0) {
      f16x8 paf[4];
      build_paf(pkPA, pkPB, paf, h);
      pv_mfma(&Vb[cur ^ 1][0], paf, oacc, q32, h);
    }

    // ---- SM(t): tree max, defer-max rescale, exp, tree sum, pack ----
    {
      float mx[16];
#pragma unroll
      for (int r = 0; r < 16; ++r) mx[r] = fmaxf(s0[r], s1[r]);
#pragma unroll
      for (int r = 0; r < 8; ++r) mx[r] = fmaxf(mx[r], mx[r + 8]);
#pragma unroll
      for (int r = 0; r < 4; ++r) mx[r] = fmaxf(mx[r], mx[r + 4]);
      float pmax = fmaxf(fmaxf(mx[0], mx[1]), fmaxf(mx[2], mx[3]));
      pmax = fmaxf(pmax, __shfl_xor(pmax, 32));

      if (!__all(pmax - mrow <= 8.f)) {          // defer-max (T13)
        float mnew = fmaxf(mrow, pmax);
        float scf = __expf(mrow - mnew);
#pragma unroll
        for (int dvt = 0; dvt < 4; ++dvt)
#pragma unroll
          for (int r = 0; r < 16; ++r) oacc[dvt][r] *= scf;
        lrow *= scf;
        mrow = mnew;
      }

      float ps[16];
#pragma unroll
      for (int r = 0; r < 16; ++r) {
        s0[r] = __expf(s0[r] - mrow);
        s1[r] = __expf(s1[r] - mrow);
        ps[r] = s0[r] + s1[r];
      }
#pragma unroll
      for (int r = 0; r < 8; ++r) ps[r] += ps[r + 8];
#pragma unroll
      for (int r = 0; r < 4; ++r) ps[r] += ps[r + 4];
      float psum = (ps[0] + ps[1]) + (ps[2] + ps[3]);
      psum += __shfl_xor(psum, 32);
      lrow += psum;

#pragma unroll
      for (int m = 0; m < 4; ++m) {
        pkPA[0][m] = __builtin_bit_cast(uint_t,
            __builtin_amdgcn_cvt_pkrtz(s0[4 * m + 0], s0[4 * m + 1]));
        pkPB[0][m] = __builtin_bit_cast(uint_t,
            __builtin_amdgcn_cvt_pkrtz(s0[4 * m + 2], s0[4 * m + 3]));
        pkPA[1][m] = __builtin_bit_cast(uint_t,
            __builtin_amdgcn_cvt_pkrtz(s1[4 * m + 0], s1[4 * m + 1]));
        pkPB[1][m] = __builtin_bit_cast(uint_t,
            __builtin_amdgcn_cvt_pkrtz(s1[4 * m + 2], s1[4 * m + 3]));
      }
    }

    asm volatile("" ::: "memory");
    __builtin_amdgcn_s_barrier();
    asm volatile("" ::: "memory");
    cur ^= 1;
  }

  // ---- epilogue: drain V(ntb-1), final PV, normalize, store ----
  asm volatile("s_waitcnt vmcnt(0)" ::: "memory");
  __builtin_amdgcn_s_barrier();
  asm volatile("" ::: "memory");
  if (ntb > 0) {
    f16x8 paf[4];
    build_paf(pkPA, pkPB, paf, h);
    pv_mfma(&Vb[cur ^ 1][0], paf, oacc, q32, h);
  }

  const float inv = 1.0f / lrow;
  float* op = Og + hbase + (size_t)qrow * DIM;
#pragma unroll
  for (int dvt = 0; dvt < 4; ++dvt)
#pragma unroll
    for (int rq = 0; rq < 4; ++rq) {
      float4 o4;
      o4.x = oacc[dvt][4 * rq + 0] * inv;
      o4.y = oacc[dvt][4 * rq + 1] * inv;
      o4.z = oacc[dvt][4 * rq + 2] * inv;
      o4.w = oacc[dvt][4 * rq + 3] * inv;
      *(float4*)(op + dvt * 32 + rq * 8 + h * 4) = o4;
    }
}

// ---------------- fallback (verified round-1 kernel) for small ws ----------------
#define QT 64
#define P_STRIDE 72
#define VT_STRIDE 76
typedef _Float16 f16x4_t __attribute__((ext_vector_type(4)));
__global__ __launch_bounds__(256, 2)
void attn_fwd_fb(const float* __restrict__ Qg, const float* __restrict__ Kg,
                 const float* __restrict__ Vg, const int* __restrict__ Mg,
                 float* __restrict__ Og) {
  __shared__ __align__(16) ushort_t K_lds[QT * DIM];
  __shared__ __align__(16) ushort_t Vt_lds[DIM * VT_STRIDE];
  __shared__ __align__(16) ushort_t P_lds[QT * P_STRIDE];
  __shared__ int M_lds[KVBLK];
  const int tid  = threadIdx.x;
  const int lane = tid & 63;
  const int w    = tid >> 6;
  const int li   = lane & 15;
  const int g    = lane >> 4;
  const int bid  = blockIdx.x;
  const int nid  = (bid & 7) * 256 + (bid >> 3);
  const int head = nid >> 5;
  const int qblk = nid & 31;
  const size_t hbase = (size_t)head * SEQ * DIM;
  const int bb = head >> 4;
  f16x8 qf[4];
  {
    const float* qp = Qg + hbase + (size_t)(qblk * QT + w * 16 + li) * DIM + g * 8;
#pragma unroll
    for (int d0 = 0; d0 < 4; ++d0) {
      float4 a = *(const float4*)(qp + d0 * 32);
      float4 b = *(const float4*)(qp + d0 * 32 + 4);
      f16x8 f;
      f[0]=(f16)a.x; f[1]=(f16)a.y; f[2]=(f16)a.z; f[3]=(f16)a.w;
      f[4]=(f16)b.x; f[5]=(f16)b.y; f[6]=(f16)b.z; f[7]=(f16)b.w;
      qf[d0] = f;
    }
  }
  float mrow[4], lrow[4];
  f32x4 oacc[8];
#pragma unroll
  for (int r = 0; r < 4; ++r) { mrow[r] = -INFINITY; lrow[r] = 0.f; }
#pragma unroll
  for (int dt = 0; dt < 8; ++dt) oacc[dt] = (f32x4)(0.f);
  for (int t = 0; t < NTMAX; ++t) {
    const int k0 = t * KVBLK;
    __syncthreads();
    {
      const float4* kgp = (const float4*)(Kg + hbase + (size_t)k0 * DIM);
#pragma unroll
      for (int rr = 0; rr < 8; ++rr) {
        int fi = rr * 256 + tid;
        int krow = fi >> 5;
        int d4 = fi & 31;
        float4 v = kgp[fi];
        union { f16 h[4]; uint2 u; } c;
        c.h[0]=(f16)v.x; c.h[1]=(f16)v.y; c.h[2]=(f16)v.z; c.h[3]=(f16)v.w;
        int off = krow * 256 + ((d4 * 8) ^ ((krow & 7) << 4));
        *(uint2*)((char*)K_lds + off) = c.u;
      }
    }
    {
      const float* vgp = Vg + hbase + (size_t)k0 * DIM;
#pragma unroll
      for (int rr = 0; rr < 16; ++rr) {
        int u = rr * 256 + tid;
        int d = u & 127;
        int k2 = (u >> 7) * 2;
        float v0 = vgp[(size_t)k2 * DIM + d];
        float v1 = vgp[(size_t)(k2 + 1) * DIM + d];
        union { f16 h[2]; unsigned int u32; } c;
        c.h[0]=(f16)v0; c.h[1]=(f16)v1;
        *(unsigned int*)(Vt_lds + d * VT_STRIDE + k2) = c.u32;
      }
    }
    if (tid < KVBLK) M_lds[tid] = Mg[(size_t)bb * SEQ + k0 + tid];
    __syncthreads();
    f32x4 sacc[4];
#pragma unroll
    for (int kt = 0; kt < 4; ++kt) sacc[kt] = (f32x4)(0.f);
#pragma unroll
    for (int kt = 0; kt < 4; ++kt) {
      const int krow = kt * 16 + li;
      const int swz = (krow & 7) << 4;
#pragma unroll
      for (int d0 = 0; d0 < 4; ++d0) {
        f16x8 kf = *(const f16x8*)((const char*)K_lds + krow * 256 + ((d0 * 64 + g * 16) ^ swz));
        sacc[kt] = __builtin_amdgcn_mfma_f32_16x16x32_f16(qf[d0], kf, sacc[kt], 0, 0, 0);
      }
    }
    float tmax[4] = {-INFINITY, -INFINITY, -INFINITY, -INFINITY};
#pragma unroll
    for (int kt = 0; kt < 4; ++kt) {
      const bool ok = (M_lds[kt * 16 + li] != 0);
#pragma unroll
      for (int r = 0; r < 4; ++r) {
        float sv = ok ? sacc[kt][r] : -1e9f;
        sacc[kt][r] = sv;
        tmax[r] = fmaxf(tmax[r], sv);
      }
    }
#pragma unroll
    for (int r = 0; r < 4; ++r) {
      tmax[r] = fmaxf(tmax[r], __shfl_xor(tmax[r], 1));
      tmax[r] = fmaxf(tmax[r], __shfl_xor(tmax[r], 2));
      tmax[r] = fmaxf(tmax[r], __shfl_xor(tmax[r], 4));
      tmax[r] = fmaxf(tmax[r], __shfl_xor(tmax[r], 8));
    }
    float sc[4], psum[4];
#pragma unroll
    for (int r = 0; r < 4; ++r) {
      float mnew = fmaxf(mrow[r], tmax[r]);
      sc[r] = __expf(mrow[r] - mnew);
      mrow[r] = mnew;
      psum[r] = 0.f;
    }
#pragma unroll
    for (int dt = 0; dt < 8; ++dt)
#pragma unroll
      for (int r = 0; r < 4; ++r) oacc[dt][r] *= sc[r];
#pragma unroll
    for (int kt = 0; kt < 4; ++kt) {
#pragma unroll
      for (int r = 0; r < 4; ++r) {
        float p = __expf(sacc[kt][r] - mrow[r]);
        psum[r] += p;
        P_lds[(w * 16 + g * 4 + r) * P_STRIDE + kt * 16 + li] =
            __builtin_bit_cast(ushort_t, (f16)p);
      }
    }
#pragma unroll
    for (int r = 0; r < 4; ++r) {
      psum[r] += __shfl_xor(psum[r], 1);
      psum[r] += __shfl_xor(psum[r], 2);
      psum[r] += __shfl_xor(psum[r], 4);
      psum[r] += __shfl_xor(psum[r], 8);
      lrow[r] = lrow[r] * sc[r] + psum[r];
    }
#pragma unroll
    for (int c = 0; c < 2; ++c) {
      f16x8 pa = *(const f16x8*)(P_lds + (w * 16 + li) * P_STRIDE + c * 32 + g * 8);
#pragma unroll
      for (int dt = 0; dt < 8; ++dt) {
        const ushort_t* vp = Vt_lds + (dt * 16 + li) * VT_STRIDE + c * 32 + g * 8;
        f16x4_t v0 = *(const f16x4_t*)vp;
        f16x4_t v1 = *(const f16x4_t*)(vp + 4);
        f16x8 vf;
        vf[0]=v0[0]; vf[1]=v0[1]; vf[2]=v0[2]; vf[3]=v0[3];
        vf[4]=v1[0]; vf[5]=v1[1]; vf[6]=v1[2]; vf[7]=v1[3];
        oacc[dt] = __builtin_amdgcn_mfma_f32_16x16x32_f16(pa, vf, oacc[dt], 0, 0, 0);
      }
    }
  }
#pragma unroll
  for (int r = 0; r < 4; ++r) {
    float inv = 1.0f / lrow[r];
    float* op = Og + hbase + (size_t)(qblk * QT + w * 16 + g * 4 + r) * DIM + li;
#pragma unroll
    for (int dt = 0; dt < 8; ++dt) op[dt * 16] = oacc[dt][r] * inv;
  }
}

extern "C" void kernel_launch(void* const* d_in, const int* in_sizes, int n_in,
                              void* d_out, int out_size, void* d_ws, size_t ws_size,
                              hipStream_t stream) {
  (void)in_sizes; (void)n_in; (void)out_size;
  const float* Q = (const float*)d_in[0];
  const float* K = (const float*)d_in[1];
  const float* V = (const float*)d_in[2];
  const int*   M = (const int*)d_in[3];
  float*       O = (float*)d_out;

  const size_t half = (size_t)2048 * TILE_BYTES;         // 33.5 MB each
  const size_t cidx_off  = 2 * half;
  const size_t ncomp_off = cidx_off + (size_t)4 * SEQ * sizeof(int);
  const size_t need = ncomp_off + 4 * sizeof(int);

  if (ws_size >= need) {
    char* Kws = (char*)d_ws;
    char* Vws = Kws + half;
    int*  cidx  = (int*)((char*)d_ws + cidx_off);
    int*  ncomp = (int*)((char*)d_ws + ncomp_off);
    scan_mask<<<dim3(4), dim3(64), 0, stream>>>(M, cidx, ncomp);
    prep_k<<<dim3(2048), dim3(256), 0, stream>>>(K, Kws, cidx, ncomp);
    prep_v<<<dim3(2048), dim3(256), 0, stream>>>(V, Vws, cidx, ncomp);
    attn_main32<<<dim3(512), dim3(512), 0, stream>>>(Q, Kws, Vws, ncomp, O);
  } else {
    attn_fwd_fb<<<dim3(2048), dim3(256), 0, stream>>>(Q, K, V, M, O);
  }
}